// Round 3
// baseline (3030.180 us; speedup 1.0000x reference)
//
#include <hip/hip_runtime.h>
#include <stdint.h>

typedef unsigned long long u64;
typedef unsigned int u32;

// anchor (w,h) per a = ratio_idx*3 + scale_idx ; ratios (.5,1,2), scales (8,16,32)
__constant__ float c_aw[9] = {184.f,368.f,736.f,128.f,256.f,512.f, 88.f,176.f,352.f};
__constant__ float c_ah[9] = { 96.f,192.f,384.f,128.f,256.f,512.f,176.f,352.f,704.f};

// ---------------- w1 transpose: w1[co][ci*9+k] -> wt[(ci*9+k)][co] ----------------
__global__ __launch_bounds__(256) void transpose_k(const float* __restrict__ w1,
                                                   float* __restrict__ wt) {
  __shared__ float t[64][65];
  const int bx = blockIdx.x & 7;    // co block (512/64)
  const int by = blockIdx.x >> 3;   // q block (4608/64)
  const int tid = threadIdx.x;
  const int co0 = bx * 64, q0 = by * 64;
  for (int e = tid; e < 4096; e += 256) {
    int co_l = e >> 6, q_l = e & 63;
    t[q_l][co_l] = w1[(size_t)(co0 + co_l) * 4608 + q0 + q_l];
  }
  __syncthreads();
  for (int e = tid; e < 4096; e += 256) {
    int q_l = e >> 6, co_l = e & 63;
    wt[(size_t)(q0 + q_l) * 512 + co0 + co_l] = t[q_l][co_l];
  }
}

// ---------------- conv1: x(4,512,96,160) * w(512,512,3,3) s2 p1 -> feat(4,512,48,80)
// block tile: 64co x 4oh x 80ow, thread tile: 8co x 10ow.
// accumulation order (c0 chunk of 8, ci, kh, kw) matches previous passing kernel bitwise.
__global__ __launch_bounds__(256, 2) void conv1_k(const float* __restrict__ x,
                                                  const float* __restrict__ wt,
                                                  const float* __restrict__ b1,
                                                  float* __restrict__ feat) {
  __shared__ float xs[8 * 9 * 164];   // [ci][ih(9)][iw(161) pad 164] = 47232 B
  __shared__ float ws2[4 * 9 * 64];   // [cil*9+k][co(64)] = 9216 B
  const int tid = threadIdx.x;
  const int owg = tid & 7;            // 8 groups of 10 ow
  const int ohl = (tid >> 3) & 3;     // 4 oh rows
  const int cog = tid >> 5;           // 8 groups of 8 co
  const int n = blockIdx.z;
  const int co0 = blockIdx.x * 64;
  const int oh0 = blockIdx.y * 4;
  const int ih_base = 2 * oh0 - 1;

  float acc[8][10];
#pragma unroll
  for (int m = 0; m < 8; ++m)
#pragma unroll
    for (int j = 0; j < 10; ++j) acc[m][j] = 0.f;

  const float* xb = x + (size_t)n * 512 * 96 * 160;

  for (int c0 = 0; c0 < 512; c0 += 8) {
    // stage x: 8 ci x 9 rows x 161 cols (col c <-> iw = c-1)
    for (int e2 = tid; e2 < 1449; e2 += 256) {
      int ih = e2 / 161;
      int c = e2 - ih * 161;
      int gih = ih_base + ih;
      int giw = c - 1;
      bool ok = ((unsigned)gih < 96u) && ((unsigned)giw < 160u);
      const float* gp = xb + ((size_t)c0 * 96 + gih) * 160 + giw;
      float* lp = &xs[ih * 164 + c];
#pragma unroll
      for (int ci = 0; ci < 8; ++ci) {
        float v = ok ? gp[(size_t)ci * 15360] : 0.f;
        lp[ci * 1476] = v;   // 9*164
      }
    }
    for (int h = 0; h < 2; ++h) {
      // stage w: 4 ci x 9 x 64co
      for (int e = tid; e < 2304; e += 256) {
        int q = e >> 6, co = e & 63;
        ws2[e] = wt[((size_t)(c0 + 4 * h) * 9 + q) * 512 + co0 + co];
      }
      __syncthreads();
      for (int cil = 0; cil < 4; ++cil) {
        const int ci = 4 * h + cil;
        const float* xrow = &xs[(ci * 9 + 2 * ohl) * 164 + owg * 20];
        const float* wrow = &ws2[cil * 9 * 64 + cog * 8];
#pragma unroll
        for (int kh = 0; kh < 3; ++kh) {
          float xv[24];
          const float* xr = xrow + kh * 164;
#pragma unroll
          for (int t4 = 0; t4 < 6; ++t4) {
            float4 t = *(const float4*)(xr + 4 * t4);
            xv[4 * t4 + 0] = t.x; xv[4 * t4 + 1] = t.y;
            xv[4 * t4 + 2] = t.z; xv[4 * t4 + 3] = t.w;
          }
#pragma unroll
          for (int kw = 0; kw < 3; ++kw) {
            const float4 w0 = *(const float4*)&wrow[(kh * 3 + kw) * 64];
            const float4 w1 = *(const float4*)&wrow[(kh * 3 + kw) * 64 + 4];
#pragma unroll
            for (int j = 0; j < 10; ++j) {
              const float xj = xv[kw + 2 * j];
              acc[0][j] += w0.x * xj; acc[1][j] += w0.y * xj;
              acc[2][j] += w0.z * xj; acc[3][j] += w0.w * xj;
              acc[4][j] += w1.x * xj; acc[5][j] += w1.y * xj;
              acc[6][j] += w1.z * xj; acc[7][j] += w1.w * xj;
            }
          }
        }
      }
      __syncthreads();
    }
  }
  // epilogue
  const int oh = oh0 + ohl;
  const int owb = owg * 10;
#pragma unroll
  for (int m = 0; m < 8; ++m) {
    const int co = co0 + cog * 8 + m;
    const float bv = b1[co];
    float* op = &feat[(((size_t)n * 512 + co) * 48 + oh) * 80 + owb];
#pragma unroll
    for (int j = 0; j < 10; j += 2) {
      float2 o2; o2.x = acc[m][j] + bv; o2.y = acc[m][j + 1] + bv;
      *(float2*)(op + j) = o2;
    }
  }
}

// ---------------- conv2: 1x1, feat -> deltas[b][pos][36] ----------------
__global__ __launch_bounds__(256) void conv2_k(const float* __restrict__ feat,
                                               const float* __restrict__ wb,
                                               const float* __restrict__ bb,
                                               float* __restrict__ deltas) {
  __shared__ float fs[16 * 128];
  __shared__ float wsb[16 * 36];
  const int tid = threadIdx.x;
  const int blk = blockIdx.x;   // 120
  const int b = blk / 30;
  const int pos0 = (blk % 30) * 128;
  const int pl = tid >> 1, cg = tid & 1;
  const int cbase = cg * 18;
  float acc[18];
#pragma unroll
  for (int j = 0; j < 18; ++j) acc[j] = 0.f;
  const float* fb = feat + (size_t)b * 512 * 3840;

  for (int c0 = 0; c0 < 512; c0 += 16) {
    for (int e = tid; e < 16 * 128; e += 256)
      fs[e] = fb[(size_t)(c0 + (e >> 7)) * 3840 + pos0 + (e & 127)];
    for (int e = tid; e < 16 * 36; e += 256) {
      int ci = e / 36, c = e - ci * 36;
      wsb[e] = wb[(size_t)c * 512 + c0 + ci];
    }
    __syncthreads();
    for (int ci = 0; ci < 16; ++ci) {
      float xv = fs[ci * 128 + pl];
#pragma unroll
      for (int j = 0; j < 18; ++j) acc[j] += xv * wsb[ci * 36 + cbase + j];
    }
    __syncthreads();
  }
  size_t o = ((size_t)b * 3840 + pos0 + pl) * 36 + cbase;
#pragma unroll
  for (int j = 0; j < 18; ++j) deltas[o + j] = acc[j] + bb[cbase + j];
}

// ---------------- conv3: 3x3 p1, channels 9..17 -> s[b][pos*9+a] ----------------
__global__ __launch_bounds__(256) void conv3_k(const float* __restrict__ feat,
                                               const float* __restrict__ wcg,
                                               const float* __restrict__ bc,
                                               float* __restrict__ s) {
  __shared__ float fs[16][3][84];   // [ci][ih][iw(-1..80)+1]
  __shared__ float wc[16][9][9];    // [ci][co][k]
  const int tid = threadIdx.x;
  const int oh = blockIdx.x;
  const int b = blockIdx.y;
  const int pos = tid % 80;
  const int cg = tid / 80;          // 0..3 (cg==3 idle for compute)
  float acc[3] = {0.f, 0.f, 0.f};
  const float* fb = feat + (size_t)b * 512 * 3840;

  for (int c0 = 0; c0 < 512; c0 += 16) {
    for (int e = tid; e < 16 * 246; e += 256) {
      int ci = e / 246;
      int r = e - ci * 246;
      int ihl = r / 82;
      int iw = r - ihl * 82 - 1;
      int gih = oh - 1 + ihl;
      float v = 0.f;
      if ((unsigned)gih < 48u && (unsigned)iw < 80u)
        v = fb[(size_t)(c0 + ci) * 3840 + gih * 80 + iw];
      fs[ci][ihl][iw + 1] = v;
    }
    for (int e = tid; e < 16 * 81; e += 256) {
      int ci = e / 81;
      int r = e - ci * 81;
      int co = r / 9;
      int k = r - co * 9;
      wc[ci][co][k] = wcg[((size_t)(9 + co) * 512 + c0 + ci) * 9 + k];
    }
    __syncthreads();
    if (cg < 3) {
      const int cb = cg * 3;
      for (int ci = 0; ci < 16; ++ci) {
#pragma unroll
        for (int kh = 0; kh < 3; ++kh) {
#pragma unroll
          for (int kw = 0; kw < 3; ++kw) {
            float xv = fs[ci][kh][pos + kw];
            acc[0] += xv * wc[ci][cb + 0][kh * 3 + kw];
            acc[1] += xv * wc[ci][cb + 1][kh * 3 + kw];
            acc[2] += xv * wc[ci][cb + 2][kh * 3 + kw];
          }
        }
      }
    }
    __syncthreads();
  }
  if (cg < 3) {
    const int cb = cg * 3;
    size_t o = (size_t)b * 34560 + ((size_t)oh * 80 + pos) * 9 + cb;
#pragma unroll
    for (int j = 0; j < 3; ++j) s[o + j] = acc[j] + bc[9 + cb + j];
  }
}

// ---------------- decode: anchors + deltas -> boxes, filtered score keys ----------------
__global__ __launch_bounds__(256) void decode_k(const float* __restrict__ deltas,
                                                const float* __restrict__ s,
                                                float* __restrict__ boxes,
                                                u64* __restrict__ keys) {
  const int g = blockIdx.x * 256 + threadIdx.x;  // < 138240 exactly
  const int b = g / 34560;
  const int i = g - b * 34560;
  const int pos = i / 9;
  const int a = i - pos * 9;
  const int h = pos / 80;
  const int w = pos - h * 80;
  const float gx = (float)(w * 32);
  const float gy = (float)(h * 32);
  const float aw = c_aw[a], ah = c_ah[a];
  const float x1a = 7.5f - 0.5f * (aw - 1.f);   // exact
  const float y1a = 7.5f - 0.5f * (ah - 1.f);   // exact
  const float ws_ = aw, hs_ = ah;               // x2-x1+1 exact
  const float cx = (gx + x1a) + 0.5f * ws_;     // exact
  const float cy = (gy + y1a) + 0.5f * hs_;     // exact

  const float* dp = &deltas[((size_t)b * 3840 + pos) * 36 + a * 4];
  const float d0 = dp[0], d1 = dp[1], d2 = dp[2], d3 = dp[3];
  const float pcx = __fadd_rn(__fmul_rn(d0, ws_), cx);
  const float pcy = __fadd_rn(__fmul_rn(d1, hs_), cy);
  const float pw = __fmul_rn(expf(d2), ws_);
  const float ph = __fmul_rn(expf(d3), hs_);
  float bx1 = __fsub_rn(pcx, __fmul_rn(0.5f, pw));
  float by1 = __fsub_rn(pcy, __fmul_rn(0.5f, ph));
  float bx2 = __fadd_rn(pcx, __fmul_rn(0.5f, pw));
  float by2 = __fadd_rn(pcy, __fmul_rn(0.5f, ph));
  bx1 = fminf(fmaxf(bx1, 0.f), 2559.f);
  by1 = fminf(fmaxf(by1, 0.f), 1535.f);
  bx2 = fminf(fmaxf(bx2, 0.f), 2559.f);
  by2 = fminf(fmaxf(by2, 0.f), 1535.f);
  const float bw = __fadd_rn(__fsub_rn(bx2, bx1), 1.f);
  const float bh = __fadd_rn(__fsub_rn(by2, by1), 1.f);
  float sc = s[g];
  if (!(bw >= 16.f && bh >= 16.f)) sc = -1e30f;

  float4 bo;
  bo.x = bx1; bo.y = by1; bo.z = bx2; bo.w = by2;
  *(float4*)&boxes[(size_t)g * 4] = bo;

  u32 sb = __float_as_uint(sc);
  u32 ou = (sb & 0x80000000u) ? ~sb : (sb | 0x80000000u);
  keys[g] = ((u64)ou << 32) | (u32)(~(u32)i);
}

// ---------------- select: exact rank-2000 key per batch via 6-pass radix histogram ----
__global__ __launch_bounds__(256) void select_k(const u64* __restrict__ keys,
                                                u64* __restrict__ Tout,
                                                int* __restrict__ cnt) {
  __shared__ u32 h[2048];
  __shared__ int s_bin;
  __shared__ u32 s_above;
  const int b = blockIdx.x;
  const int tid = threadIdx.x;
  const u64* kb = keys + (size_t)b * 34560;
  u64 prefix = 0, pmask = 0;
  int rank = 2000;

#pragma unroll 1
  for (int pass = 0; pass < 6; ++pass) {
    int shift = 53 - 11 * pass;
    if (shift < 0) shift = 0;
    // clear
#pragma unroll
    for (int q = 0; q < 8; ++q) h[tid + 256 * q] = 0;
    __syncthreads();
    // histogram of prefix-matching keys on 11 bits at `shift`
    for (int i = tid; i < 34560; i += 256) {
      u64 k = kb[i];
      if ((k & pmask) == prefix)
        atomicAdd(&h[(u32)((k >> shift) & 2047ull)], 1u);
    }
    __syncthreads();
    // suffix sum: h[i] = count with bin >= i
    for (int off = 1; off < 2048; off <<= 1) {
      u32 t[8];
#pragma unroll
      for (int q = 0; q < 8; ++q) {
        int i = tid + 256 * q;
        t[q] = h[i] + ((i + off < 2048) ? h[i + off] : 0u);
      }
      __syncthreads();
#pragma unroll
      for (int q = 0; q < 8; ++q) h[tid + 256 * q] = t[q];
      __syncthreads();
    }
    // find bin where suffix crosses rank
#pragma unroll
    for (int q = 0; q < 8; ++q) {
      int i = tid + 256 * q;
      u32 Si = h[i];
      u32 Sn = (i < 2047) ? h[i + 1] : 0u;
      if ((int)Si >= rank && (int)Sn < rank) { s_bin = i; s_above = Sn; }
    }
    __syncthreads();
    rank -= (int)s_above;
    prefix |= ((u64)(u32)s_bin) << shift;
    pmask |= (2047ull << shift);
    __syncthreads();
  }
  if (tid == 0) { Tout[b] = prefix; cnt[b] = 0; }
}

// ---------------- compact: keys >= T[b] (exactly 2000 per batch, unordered) ----------
__global__ __launch_bounds__(256) void compact_k(const u64* __restrict__ keys,
                                                 const u64* __restrict__ T,
                                                 int* __restrict__ cnt,
                                                 u64* __restrict__ sel) {
  const int g = blockIdx.x * 256 + threadIdx.x;  // < 138240 exactly
  const int b = g / 34560;
  u64 k = keys[g];
  if (k >= T[b]) {
    int p = atomicAdd(&cnt[b], 1);
    sel[(size_t)b * 2048 + p] = k;
  }
}

// ---------------- fused sort(2048) + greedy NMS per batch ----------------
__global__ __launch_bounds__(256) void nms2_k(const u64* __restrict__ sel,
                                              const float* __restrict__ boxes,
                                              float* __restrict__ out) {
  __shared__ u64 K[2048];
  __shared__ float bx1[2000], by1[2000], bx2[2000], by2[2000], ar[2000];
  __shared__ unsigned char val[2000];
  __shared__ int s_pick, s_cur, s_cnt;
  const int b = blockIdx.x;
  const int tid = threadIdx.x;

  for (int i = tid; i < 2048; i += 256)
    K[i] = (i < 2000) ? sel[(size_t)b * 2048 + i] : 0ull;
  __syncthreads();
  // bitonic sort descending
  for (int k2 = 2; k2 <= 2048; k2 <<= 1) {
    for (int j = k2 >> 1; j > 0; j >>= 1) {
      for (int i = tid; i < 2048; i += 256) {
        int l = i ^ j;
        if (l > i) {
          u64 a = K[i], c = K[l];
          bool up = ((i & k2) == 0);
          if (up ? (a < c) : (a > c)) { K[i] = c; K[l] = a; }
        }
      }
      __syncthreads();
    }
  }
  // extract boxes/validity in score order
  for (int i = tid; i < 2000; i += 256) {
    u64 key = K[i];
    u32 ou = (u32)(key >> 32);
    int idx = (int)(~(u32)key);
    u32 sb = (ou & 0x80000000u) ? (ou & 0x7FFFFFFFu) : ~ou;
    float sc = __uint_as_float(sb);
    const float4 bo = *(const float4*)&boxes[((size_t)b * 34560 + idx) * 4];
    bx1[i] = bo.x; by1[i] = bo.y; bx2[i] = bo.z; by2[i] = bo.w;
    ar[i] = __fmul_rn(__fadd_rn(__fsub_rn(bo.z, bo.x), 1.f),
                      __fadd_rn(__fsub_rn(bo.w, bo.y), 1.f));
    val[i] = (sc > -5e29f) ? 1 : 0;
  }
  if (tid == 0) { s_cur = 0; s_cnt = 0; }
  __syncthreads();

  for (int t = 0; t < 300; ++t) {
    if (tid == 0) {
      int c = s_cur;
      while (c < 2000 && !val[c]) ++c;
      if (c < 2000) { s_pick = c; s_cur = c + 1; s_cnt = t + 1; }
      else s_pick = -1;
    }
    __syncthreads();
    const int p = s_pick;
    if (p < 0) break;
    const float px1 = bx1[p], py1 = by1[p], px2 = bx2[p], py2 = by2[p], pa = ar[p];
    if (tid == 0) {
      float* row = out + ((size_t)b * 300 + t) * 5;
      row[0] = (float)b; row[1] = px1; row[2] = py1; row[3] = px2; row[4] = py2;
    }
    for (int jj = p + 1 + tid; jj < 2000; jj += 256) {
      if (val[jj]) {
        float iw = __fadd_rn(__fsub_rn(fminf(px2, bx2[jj]), fmaxf(px1, bx1[jj])), 1.f);
        iw = fmaxf(0.f, iw);
        float ih = __fadd_rn(__fsub_rn(fminf(py2, by2[jj]), fmaxf(py1, by1[jj])), 1.f);
        ih = fmaxf(0.f, ih);
        float inter = __fmul_rn(iw, ih);
        float denom = __fsub_rn(__fadd_rn(pa, ar[jj]), inter);
        float iou = __fdiv_rn(inter, denom);
        if (iou > 0.7f) val[jj] = 0;
      }
    }
    __syncthreads();
  }

  __syncthreads();
  const int cnt = s_cnt;
  for (int t = cnt + tid; t < 300; t += 256) {
    float* row = out + ((size_t)b * 300 + t) * 5;
    row[0] = (float)b; row[1] = 0.f; row[2] = 0.f; row[3] = 0.f; row[4] = 0.f;
  }
  if (tid == 0) out[6000 + b] = (float)cnt;
}

// ---------------- launcher ----------------
extern "C" void kernel_launch(void* const* d_in, const int* in_sizes, int n_in,
                              void* d_out, int out_size, void* d_ws, size_t ws_size,
                              hipStream_t stream) {
  const float* x  = (const float*)d_in[0];
  const float* w1 = (const float*)d_in[1];
  const float* b1 = (const float*)d_in[2];
  const float* wb = (const float*)d_in[3];
  const float* bb = (const float*)d_in[4];
  const float* wc = (const float*)d_in[5];
  const float* bc = (const float*)d_in[6];
  float* out = (float*)d_out;
  char* ws = (char*)d_ws;

  float* feat   = (float*)(ws + 0);           // 31,457,280 B
  float* wt     = (float*)(ws + 31457280);    //  9,437,184 B
  float* deltas = (float*)(ws + 40894464);    //  2,211,840 B
  float* s      = (float*)(ws + 43106304);    //    552,960 B
  float* boxes  = (float*)(ws + 43659264);    //  2,211,840 B
  u64*   keys   = (u64*)  (ws + 45871104);    //  1,105,920 B
  u64*   T      = (u64*)  (ws + 46977024);    //         32 B
  int*   cnt    = (int*)  (ws + 46977056);    //         32 B
  u64*   sel    = (u64*)  (ws + 46977088);    //     65,536 B

  hipLaunchKernelGGL(transpose_k, dim3(576), dim3(256), 0, stream, w1, wt);
  hipLaunchKernelGGL(conv1_k, dim3(8, 12, 4), dim3(256), 0, stream, x, wt, b1, feat);
  hipLaunchKernelGGL(conv2_k, dim3(120), dim3(256), 0, stream, feat, wb, bb, deltas);
  hipLaunchKernelGGL(conv3_k, dim3(48, 4), dim3(256), 0, stream, feat, wc, bc, s);
  hipLaunchKernelGGL(decode_k, dim3(540), dim3(256), 0, stream, deltas, s, boxes, keys);
  hipLaunchKernelGGL(select_k, dim3(4), dim3(256), 0, stream, keys, T, cnt);
  hipLaunchKernelGGL(compact_k, dim3(540), dim3(256), 0, stream, keys, T, cnt, sel);
  hipLaunchKernelGGL(nms2_k, dim3(4), dim3(256), 0, stream, sel, boxes, out);
}

// Round 4
// 3001.643 us; speedup vs baseline: 1.0095x; 1.0095x over previous
//
#include <hip/hip_runtime.h>
#include <stdint.h>

typedef unsigned long long u64;
typedef unsigned int u32;

// anchor (w,h) per a = ratio_idx*3 + scale_idx ; ratios (.5,1,2), scales (8,16,32)
__constant__ float c_aw[9] = {184.f,368.f,736.f,128.f,256.f,512.f, 88.f,176.f,352.f};
__constant__ float c_ah[9] = { 96.f,192.f,384.f,128.f,256.f,512.f,176.f,352.f,704.f};

// ---------------- w1 transpose: w1[co][ci*9+k] -> wt[(ci*9+k)][co] ----------------
__global__ __launch_bounds__(256) void transpose_k(const float* __restrict__ w1,
                                                   float* __restrict__ wt) {
  __shared__ float t[64][65];
  const int bx = blockIdx.x & 7;    // co block (512/64)
  const int by = blockIdx.x >> 3;   // q block (4608/64)
  const int tid = threadIdx.x;
  const int co0 = bx * 64, q0 = by * 64;
  for (int e = tid; e < 4096; e += 256) {
    int co_l = e >> 6, q_l = e & 63;
    t[q_l][co_l] = w1[(size_t)(co0 + co_l) * 4608 + q0 + q_l];
  }
  __syncthreads();
  for (int e = tid; e < 4096; e += 256) {
    int q_l = e >> 6, co_l = e & 63;
    wt[(size_t)(q0 + q_l) * 512 + co0 + co_l] = t[q_l][co_l];
  }
}

// ---------------- conv1: x(4,512,96,160) * w(512,512,3,3) s2 p1 -> feat(4,512,48,80)
// block tile: 64co x 4oh x 80ow, thread tile: 8co x 10ow.
// accumulation order (c0 chunk of 8, ci, kh, kw) matches previous passing kernel bitwise.
__global__ __launch_bounds__(256, 2) void conv1_k(const float* __restrict__ x,
                                                  const float* __restrict__ wt,
                                                  const float* __restrict__ b1,
                                                  float* __restrict__ feat) {
  __shared__ float xs[8 * 9 * 164];   // [ci][ih(9)][iw(161) pad 164] = 47232 B
  __shared__ float ws2[4 * 9 * 64];   // [cil*9+k][co(64)] = 9216 B
  const int tid = threadIdx.x;
  const int owg = tid & 7;            // 8 groups of 10 ow
  const int ohl = (tid >> 3) & 3;     // 4 oh rows
  const int cog = tid >> 5;           // 8 groups of 8 co
  const int n = blockIdx.z;
  const int co0 = blockIdx.x * 64;
  const int oh0 = blockIdx.y * 4;
  const int ih_base = 2 * oh0 - 1;

  float acc[8][10];
#pragma unroll
  for (int m = 0; m < 8; ++m)
#pragma unroll
    for (int j = 0; j < 10; ++j) acc[m][j] = 0.f;

  const float* xb = x + (size_t)n * 512 * 96 * 160;

  for (int c0 = 0; c0 < 512; c0 += 8) {
    // stage x: 8 ci x 9 rows x 161 cols (col c <-> iw = c-1)
    for (int e2 = tid; e2 < 1449; e2 += 256) {
      int ih = e2 / 161;
      int c = e2 - ih * 161;
      int gih = ih_base + ih;
      int giw = c - 1;
      bool ok = ((unsigned)gih < 96u) && ((unsigned)giw < 160u);
      const float* gp = xb + ((size_t)c0 * 96 + gih) * 160 + giw;
      float* lp = &xs[ih * 164 + c];
#pragma unroll
      for (int ci = 0; ci < 8; ++ci) {
        float v = ok ? gp[(size_t)ci * 15360] : 0.f;
        lp[ci * 1476] = v;   // 9*164
      }
    }
    for (int h = 0; h < 2; ++h) {
      // stage w: 4 ci x 9 x 64co
      for (int e = tid; e < 2304; e += 256) {
        int q = e >> 6, co = e & 63;
        ws2[e] = wt[((size_t)(c0 + 4 * h) * 9 + q) * 512 + co0 + co];
      }
      __syncthreads();
      for (int cil = 0; cil < 4; ++cil) {
        const int ci = 4 * h + cil;
        const float* xrow = &xs[(ci * 9 + 2 * ohl) * 164 + owg * 20];
        const float* wrow = &ws2[cil * 9 * 64 + cog * 8];
#pragma unroll
        for (int kh = 0; kh < 3; ++kh) {
          float xv[24];
          const float* xr = xrow + kh * 164;
#pragma unroll
          for (int t4 = 0; t4 < 6; ++t4) {
            float4 t = *(const float4*)(xr + 4 * t4);
            xv[4 * t4 + 0] = t.x; xv[4 * t4 + 1] = t.y;
            xv[4 * t4 + 2] = t.z; xv[4 * t4 + 3] = t.w;
          }
#pragma unroll
          for (int kw = 0; kw < 3; ++kw) {
            const float4 w0 = *(const float4*)&wrow[(kh * 3 + kw) * 64];
            const float4 w1 = *(const float4*)&wrow[(kh * 3 + kw) * 64 + 4];
#pragma unroll
            for (int j = 0; j < 10; ++j) {
              const float xj = xv[kw + 2 * j];
              acc[0][j] += w0.x * xj; acc[1][j] += w0.y * xj;
              acc[2][j] += w0.z * xj; acc[3][j] += w0.w * xj;
              acc[4][j] += w1.x * xj; acc[5][j] += w1.y * xj;
              acc[6][j] += w1.z * xj; acc[7][j] += w1.w * xj;
            }
          }
        }
      }
      __syncthreads();
    }
  }
  // epilogue
  const int oh = oh0 + ohl;
  const int owb = owg * 10;
#pragma unroll
  for (int m = 0; m < 8; ++m) {
    const int co = co0 + cog * 8 + m;
    const float bv = b1[co];
    float* op = &feat[(((size_t)n * 512 + co) * 48 + oh) * 80 + owb];
#pragma unroll
    for (int j = 0; j < 10; j += 2) {
      float2 o2; o2.x = acc[m][j] + bv; o2.y = acc[m][j + 1] + bv;
      *(float2*)(op + j) = o2;
    }
  }
}

// ---------------- conv2: 1x1, feat -> deltas[b][pos][36] ----------------
__global__ __launch_bounds__(256) void conv2_k(const float* __restrict__ feat,
                                               const float* __restrict__ wb,
                                               const float* __restrict__ bb,
                                               float* __restrict__ deltas) {
  __shared__ float fs[16 * 128];
  __shared__ float wsb[16 * 36];
  const int tid = threadIdx.x;
  const int blk = blockIdx.x;   // 120
  const int b = blk / 30;
  const int pos0 = (blk % 30) * 128;
  const int pl = tid >> 1, cg = tid & 1;
  const int cbase = cg * 18;
  float acc[18];
#pragma unroll
  for (int j = 0; j < 18; ++j) acc[j] = 0.f;
  const float* fb = feat + (size_t)b * 512 * 3840;

  for (int c0 = 0; c0 < 512; c0 += 16) {
    for (int e = tid; e < 16 * 128; e += 256)
      fs[e] = fb[(size_t)(c0 + (e >> 7)) * 3840 + pos0 + (e & 127)];
    for (int e = tid; e < 16 * 36; e += 256) {
      int ci = e / 36, c = e - ci * 36;
      wsb[e] = wb[(size_t)c * 512 + c0 + ci];
    }
    __syncthreads();
    for (int ci = 0; ci < 16; ++ci) {
      float xv = fs[ci * 128 + pl];
#pragma unroll
      for (int j = 0; j < 18; ++j) acc[j] += xv * wsb[ci * 36 + cbase + j];
    }
    __syncthreads();
  }
  size_t o = ((size_t)b * 3840 + pos0 + pl) * 36 + cbase;
#pragma unroll
  for (int j = 0; j < 18; ++j) deltas[o + j] = acc[j] + bb[cbase + j];
}

// ---------------- conv3: 3x3 p1, channels 9..17 -> s[b][pos*9+a] ----------------
__global__ __launch_bounds__(256) void conv3_k(const float* __restrict__ feat,
                                               const float* __restrict__ wcg,
                                               const float* __restrict__ bc,
                                               float* __restrict__ s) {
  __shared__ float fs[16][3][84];   // [ci][ih][iw(-1..80)+1]
  __shared__ float wc[16][9][9];    // [ci][co][k]
  const int tid = threadIdx.x;
  const int oh = blockIdx.x;
  const int b = blockIdx.y;
  const int pos = tid % 80;
  const int cg = tid / 80;          // 0..3 (cg==3 idle for compute)
  float acc[3] = {0.f, 0.f, 0.f};
  const float* fb = feat + (size_t)b * 512 * 3840;

  for (int c0 = 0; c0 < 512; c0 += 16) {
    for (int e = tid; e < 16 * 246; e += 256) {
      int ci = e / 246;
      int r = e - ci * 246;
      int ihl = r / 82;
      int iw = r - ihl * 82 - 1;
      int gih = oh - 1 + ihl;
      float v = 0.f;
      if ((unsigned)gih < 48u && (unsigned)iw < 80u)
        v = fb[(size_t)(c0 + ci) * 3840 + gih * 80 + iw];
      fs[ci][ihl][iw + 1] = v;
    }
    for (int e = tid; e < 16 * 81; e += 256) {
      int ci = e / 81;
      int r = e - ci * 81;
      int co = r / 9;
      int k = r - co * 9;
      wc[ci][co][k] = wcg[((size_t)(9 + co) * 512 + c0 + ci) * 9 + k];
    }
    __syncthreads();
    if (cg < 3) {
      const int cb = cg * 3;
      for (int ci = 0; ci < 16; ++ci) {
#pragma unroll
        for (int kh = 0; kh < 3; ++kh) {
#pragma unroll
          for (int kw = 0; kw < 3; ++kw) {
            float xv = fs[ci][kh][pos + kw];
            acc[0] += xv * wc[ci][cb + 0][kh * 3 + kw];
            acc[1] += xv * wc[ci][cb + 1][kh * 3 + kw];
            acc[2] += xv * wc[ci][cb + 2][kh * 3 + kw];
          }
        }
      }
    }
    __syncthreads();
  }
  if (cg < 3) {
    const int cb = cg * 3;
    size_t o = (size_t)b * 34560 + ((size_t)oh * 80 + pos) * 9 + cb;
#pragma unroll
    for (int j = 0; j < 3; ++j) s[o + j] = acc[j] + bc[9 + cb + j];
  }
}

// ---------------- decode: anchors + deltas -> boxes, filtered score keys ----------------
__global__ __launch_bounds__(256) void decode_k(const float* __restrict__ deltas,
                                                const float* __restrict__ s,
                                                float* __restrict__ boxes,
                                                u64* __restrict__ keys) {
  const int g = blockIdx.x * 256 + threadIdx.x;  // < 138240 exactly
  const int b = g / 34560;
  const int i = g - b * 34560;
  const int pos = i / 9;
  const int a = i - pos * 9;
  const int h = pos / 80;
  const int w = pos - h * 80;
  const float gx = (float)(w * 32);
  const float gy = (float)(h * 32);
  const float aw = c_aw[a], ah = c_ah[a];
  const float x1a = 7.5f - 0.5f * (aw - 1.f);   // exact
  const float y1a = 7.5f - 0.5f * (ah - 1.f);   // exact
  const float ws_ = aw, hs_ = ah;               // x2-x1+1 exact
  const float cx = (gx + x1a) + 0.5f * ws_;     // exact
  const float cy = (gy + y1a) + 0.5f * hs_;     // exact

  const float* dp = &deltas[((size_t)b * 3840 + pos) * 36 + a * 4];
  const float d0 = dp[0], d1 = dp[1], d2 = dp[2], d3 = dp[3];
  const float pcx = __fadd_rn(__fmul_rn(d0, ws_), cx);
  const float pcy = __fadd_rn(__fmul_rn(d1, hs_), cy);
  const float pw = __fmul_rn(expf(d2), ws_);
  const float ph = __fmul_rn(expf(d3), hs_);
  float bx1 = __fsub_rn(pcx, __fmul_rn(0.5f, pw));
  float by1 = __fsub_rn(pcy, __fmul_rn(0.5f, ph));
  float bx2 = __fadd_rn(pcx, __fmul_rn(0.5f, pw));
  float by2 = __fadd_rn(pcy, __fmul_rn(0.5f, ph));
  bx1 = fminf(fmaxf(bx1, 0.f), 2559.f);
  by1 = fminf(fmaxf(by1, 0.f), 1535.f);
  bx2 = fminf(fmaxf(bx2, 0.f), 2559.f);
  by2 = fminf(fmaxf(by2, 0.f), 1535.f);
  const float bw = __fadd_rn(__fsub_rn(bx2, bx1), 1.f);
  const float bh = __fadd_rn(__fsub_rn(by2, by1), 1.f);
  float sc = s[g];
  if (!(bw >= 16.f && bh >= 16.f)) sc = -1e30f;

  float4 bo;
  bo.x = bx1; bo.y = by1; bo.z = bx2; bo.w = by2;
  *(float4*)&boxes[(size_t)g * 4] = bo;

  u32 sb = __float_as_uint(sc);
  u32 ou = (sb & 0x80000000u) ? ~sb : (sb | 0x80000000u);
  keys[g] = ((u64)ou << 32) | (u32)(~(u32)i);
}

// ---------------- select: exact rank-2000 key per batch via 6-pass radix histogram ----
__global__ __launch_bounds__(256) void select_k(const u64* __restrict__ keys,
                                                u64* __restrict__ Tout,
                                                int* __restrict__ cnt) {
  __shared__ u32 h[2048];
  __shared__ int s_bin;
  __shared__ u32 s_above;
  const int b = blockIdx.x;
  const int tid = threadIdx.x;
  const u64* kb = keys + (size_t)b * 34560;
  u64 prefix = 0, pmask = 0;
  int rank = 2000;

#pragma unroll 1
  for (int pass = 0; pass < 6; ++pass) {
    int shift = 53 - 11 * pass;
    if (shift < 0) shift = 0;
    // clear
#pragma unroll
    for (int q = 0; q < 8; ++q) h[tid + 256 * q] = 0;
    __syncthreads();
    // histogram of prefix-matching keys on 11 bits at `shift`
    for (int i = tid; i < 34560; i += 256) {
      u64 k = kb[i];
      if ((k & pmask) == prefix)
        atomicAdd(&h[(u32)((k >> shift) & 2047ull)], 1u);
    }
    __syncthreads();
    // suffix sum: h[i] = count with bin >= i
    for (int off = 1; off < 2048; off <<= 1) {
      u32 t[8];
#pragma unroll
      for (int q = 0; q < 8; ++q) {
        int i = tid + 256 * q;
        t[q] = h[i] + ((i + off < 2048) ? h[i + off] : 0u);
      }
      __syncthreads();
#pragma unroll
      for (int q = 0; q < 8; ++q) h[tid + 256 * q] = t[q];
      __syncthreads();
    }
    // find bin where suffix crosses rank
#pragma unroll
    for (int q = 0; q < 8; ++q) {
      int i = tid + 256 * q;
      u32 Si = h[i];
      u32 Sn = (i < 2047) ? h[i + 1] : 0u;
      if ((int)Si >= rank && (int)Sn < rank) { s_bin = i; s_above = Sn; }
    }
    __syncthreads();
    rank -= (int)s_above;
    prefix |= ((u64)(u32)s_bin) << shift;
    pmask |= (2047ull << shift);
    __syncthreads();
  }
  if (tid == 0) { Tout[b] = prefix; cnt[b] = 0; }
}

// ---------------- compact: keys >= T[b] (exactly 2000 per batch, unordered) ----------
__global__ __launch_bounds__(256) void compact_k(const u64* __restrict__ keys,
                                                 const u64* __restrict__ T,
                                                 int* __restrict__ cnt,
                                                 u64* __restrict__ sel) {
  const int g = blockIdx.x * 256 + threadIdx.x;  // < 138240 exactly
  const int b = g / 34560;
  u64 k = keys[g];
  if (k >= T[b]) {
    int p = atomicAdd(&cnt[b], 1);
    sel[(size_t)b * 2048 + p] = k;
  }
}

// ---------------- fused sort(2048) + greedy NMS per batch ----------------
__global__ __launch_bounds__(256) void nms2_k(const u64* __restrict__ sel,
                                              const float* __restrict__ boxes,
                                              float* __restrict__ out) {
  __shared__ u64 K[2048];
  __shared__ float bx1[2000], by1[2000], bx2[2000], by2[2000], ar[2000];
  __shared__ unsigned char val[2000];
  __shared__ int s_pick, s_cur, s_cnt;
  const int b = blockIdx.x;
  const int tid = threadIdx.x;

  for (int i = tid; i < 2048; i += 256)
    K[i] = (i < 2000) ? sel[(size_t)b * 2048 + i] : 0ull;
  __syncthreads();
  // bitonic sort descending
  for (int k2 = 2; k2 <= 2048; k2 <<= 1) {
    for (int j = k2 >> 1; j > 0; j >>= 1) {
      for (int i = tid; i < 2048; i += 256) {
        int l = i ^ j;
        if (l > i) {
          u64 a = K[i], c = K[l];
          bool up = ((i & k2) == 0);
          if (up ? (a < c) : (a > c)) { K[i] = c; K[l] = a; }
        }
      }
      __syncthreads();
    }
  }
  // extract boxes/validity in score order
  for (int i = tid; i < 2000; i += 256) {
    u64 key = K[i];
    u32 ou = (u32)(key >> 32);
    int idx = (int)(~(u32)key);
    u32 sb = (ou & 0x80000000u) ? (ou & 0x7FFFFFFFu) : ~ou;
    float sc = __uint_as_float(sb);
    const float4 bo = *(const float4*)&boxes[((size_t)b * 34560 + idx) * 4];
    bx1[i] = bo.x; by1[i] = bo.y; bx2[i] = bo.z; by2[i] = bo.w;
    ar[i] = __fmul_rn(__fadd_rn(__fsub_rn(bo.z, bo.x), 1.f),
                      __fadd_rn(__fsub_rn(bo.w, bo.y), 1.f));
    val[i] = (sc > -5e29f) ? 1 : 0;
  }
  if (tid == 0) { s_cur = 0; s_cnt = 0; }
  __syncthreads();

  for (int t = 0; t < 300; ++t) {
    if (tid == 0) {
      int c = s_cur;
      while (c < 2000 && !val[c]) ++c;
      if (c < 2000) { s_pick = c; s_cur = c + 1; s_cnt = t + 1; }
      else s_pick = -1;
    }
    __syncthreads();
    const int p = s_pick;
    if (p < 0) break;
    const float px1 = bx1[p], py1 = by1[p], px2 = bx2[p], py2 = by2[p], pa = ar[p];
    if (tid == 0) {
      float* row = out + ((size_t)b * 300 + t) * 5;
      row[0] = (float)b; row[1] = px1; row[2] = py1; row[3] = px2; row[4] = py2;
    }
    for (int jj = p + 1 + tid; jj < 2000; jj += 256) {
      if (val[jj]) {
        float iw = __fadd_rn(__fsub_rn(fminf(px2, bx2[jj]), fmaxf(px1, bx1[jj])), 1.f);
        iw = fmaxf(0.f, iw);
        float ih = __fadd_rn(__fsub_rn(fminf(py2, by2[jj]), fmaxf(py1, by1[jj])), 1.f);
        ih = fmaxf(0.f, ih);
        float inter = __fmul_rn(iw, ih);
        float denom = __fsub_rn(__fadd_rn(pa, ar[jj]), inter);
        float iou = __fdiv_rn(inter, denom);
        if (iou > 0.7f) val[jj] = 0;
      }
    }
    __syncthreads();
  }

  __syncthreads();
  const int cnt = s_cnt;
  for (int t = cnt + tid; t < 300; t += 256) {
    float* row = out + ((size_t)b * 300 + t) * 5;
    row[0] = (float)b; row[1] = 0.f; row[2] = 0.f; row[3] = 0.f; row[4] = 0.f;
  }
  if (tid == 0) out[6000 + b] = (float)cnt;
}

// ---------------- launcher ----------------
extern "C" void kernel_launch(void* const* d_in, const int* in_sizes, int n_in,
                              void* d_out, int out_size, void* d_ws, size_t ws_size,
                              hipStream_t stream) {
  const float* x  = (const float*)d_in[0];
  const float* w1 = (const float*)d_in[1];
  const float* b1 = (const float*)d_in[2];
  const float* wb = (const float*)d_in[3];
  const float* bb = (const float*)d_in[4];
  const float* wc = (const float*)d_in[5];
  const float* bc = (const float*)d_in[6];
  float* out = (float*)d_out;
  char* ws = (char*)d_ws;

  float* feat   = (float*)(ws + 0);           // 31,457,280 B
  float* wt     = (float*)(ws + 31457280);    //  9,437,184 B
  float* deltas = (float*)(ws + 40894464);    //  2,211,840 B
  float* s      = (float*)(ws + 43106304);    //    552,960 B
  float* boxes  = (float*)(ws + 43659264);    //  2,211,840 B
  u64*   keys   = (u64*)  (ws + 45871104);    //  1,105,920 B
  u64*   T      = (u64*)  (ws + 46977024);    //         32 B
  int*   cnt    = (int*)  (ws + 46977056);    //         32 B
  u64*   sel    = (u64*)  (ws + 46977088);    //     65,536 B

  hipLaunchKernelGGL(transpose_k, dim3(576), dim3(256), 0, stream, w1, wt);
  hipLaunchKernelGGL(conv1_k, dim3(8, 12, 4), dim3(256), 0, stream, x, wt, b1, feat);
  hipLaunchKernelGGL(conv2_k, dim3(120), dim3(256), 0, stream, feat, wb, bb, deltas);
  hipLaunchKernelGGL(conv3_k, dim3(48, 4), dim3(256), 0, stream, feat, wc, bc, s);
  hipLaunchKernelGGL(decode_k, dim3(540), dim3(256), 0, stream, deltas, s, boxes, keys);
  hipLaunchKernelGGL(select_k, dim3(4), dim3(256), 0, stream, keys, T, cnt);
  hipLaunchKernelGGL(compact_k, dim3(540), dim3(256), 0, stream, keys, T, cnt, sel);
  hipLaunchKernelGGL(nms2_k, dim3(4), dim3(256), 0, stream, sel, boxes, out);
}

// Round 5
// 2997.494 us; speedup vs baseline: 1.0109x; 1.0014x over previous
//
#include <hip/hip_runtime.h>
#include <stdint.h>

typedef unsigned long long u64;
typedef unsigned int u32;

// anchor (w,h) per a = ratio_idx*3 + scale_idx ; ratios (.5,1,2), scales (8,16,32)
__constant__ float c_aw[9] = {184.f,368.f,736.f,128.f,256.f,512.f, 88.f,176.f,352.f};
__constant__ float c_ah[9] = { 96.f,192.f,384.f,128.f,256.f,512.f,176.f,352.f,704.f};

// ---------------- w1 transpose: w1[co][ci*9+k] -> wt[(ci*9+k)][co] ----------------
__global__ __launch_bounds__(256) void transpose_k(const float* __restrict__ w1,
                                                   float* __restrict__ wt) {
  __shared__ float t[64][65];
  const int bx = blockIdx.x & 7;    // co block (512/64)
  const int by = blockIdx.x >> 3;   // q block (4608/64)
  const int tid = threadIdx.x;
  const int co0 = bx * 64, q0 = by * 64;
  for (int e = tid; e < 4096; e += 256) {
    int co_l = e >> 6, q_l = e & 63;
    t[q_l][co_l] = w1[(size_t)(co0 + co_l) * 4608 + q0 + q_l];
  }
  __syncthreads();
  for (int e = tid; e < 4096; e += 256) {
    int q_l = e >> 6, co_l = e & 63;
    wt[(size_t)(q0 + q_l) * 512 + co0 + co_l] = t[q_l][co_l];
  }
}

// ---------------- conv1: x(4,512,96,160) * w(512,512,3,3) s2 p1 -> feat(4,512,48,80)
// block tile: 64co x 4oh x 80ow, thread tile: 8co x 10ow.
// accumulation order (c0 chunk of 8, ci, kh, kw) matches previous passing kernel bitwise.
__global__ __launch_bounds__(256, 2) void conv1_k(const float* __restrict__ x,
                                                  const float* __restrict__ wt,
                                                  const float* __restrict__ b1,
                                                  float* __restrict__ feat) {
  __shared__ float xs[8 * 9 * 164];   // [ci][ih(9)][iw(161) pad 164] = 47232 B
  __shared__ float ws2[4 * 9 * 64];   // [cil*9+k][co(64)] = 9216 B
  const int tid = threadIdx.x;
  const int owg = tid & 7;            // 8 groups of 10 ow
  const int ohl = (tid >> 3) & 3;     // 4 oh rows
  const int cog = tid >> 5;           // 8 groups of 8 co
  const int n = blockIdx.z;
  const int co0 = blockIdx.x * 64;
  const int oh0 = blockIdx.y * 4;
  const int ih_base = 2 * oh0 - 1;

  float acc[8][10];
#pragma unroll
  for (int m = 0; m < 8; ++m)
#pragma unroll
    for (int j = 0; j < 10; ++j) acc[m][j] = 0.f;

  const float* xb = x + (size_t)n * 512 * 96 * 160;

  for (int c0 = 0; c0 < 512; c0 += 8) {
    // stage x: 8 ci x 9 rows x 161 cols (col c <-> iw = c-1)
    for (int e2 = tid; e2 < 1449; e2 += 256) {
      int ih = e2 / 161;
      int c = e2 - ih * 161;
      int gih = ih_base + ih;
      int giw = c - 1;
      bool ok = ((unsigned)gih < 96u) && ((unsigned)giw < 160u);
      const float* gp = xb + ((size_t)c0 * 96 + gih) * 160 + giw;
      float* lp = &xs[ih * 164 + c];
#pragma unroll
      for (int ci = 0; ci < 8; ++ci) {
        float v = ok ? gp[(size_t)ci * 15360] : 0.f;
        lp[ci * 1476] = v;   // 9*164
      }
    }
    for (int h = 0; h < 2; ++h) {
      // stage w: 4 ci x 9 x 64co
      for (int e = tid; e < 2304; e += 256) {
        int q = e >> 6, co = e & 63;
        ws2[e] = wt[((size_t)(c0 + 4 * h) * 9 + q) * 512 + co0 + co];
      }
      __syncthreads();
      for (int cil = 0; cil < 4; ++cil) {
        const int ci = 4 * h + cil;
        const float* xrow = &xs[(ci * 9 + 2 * ohl) * 164 + owg * 20];
        const float* wrow = &ws2[cil * 9 * 64 + cog * 8];
#pragma unroll
        for (int kh = 0; kh < 3; ++kh) {
          float xv[24];
          const float* xr = xrow + kh * 164;
#pragma unroll
          for (int t4 = 0; t4 < 6; ++t4) {
            float4 t = *(const float4*)(xr + 4 * t4);
            xv[4 * t4 + 0] = t.x; xv[4 * t4 + 1] = t.y;
            xv[4 * t4 + 2] = t.z; xv[4 * t4 + 3] = t.w;
          }
#pragma unroll
          for (int kw = 0; kw < 3; ++kw) {
            const float4 w0 = *(const float4*)&wrow[(kh * 3 + kw) * 64];
            const float4 w1 = *(const float4*)&wrow[(kh * 3 + kw) * 64 + 4];
#pragma unroll
            for (int j = 0; j < 10; ++j) {
              const float xj = xv[kw + 2 * j];
              acc[0][j] += w0.x * xj; acc[1][j] += w0.y * xj;
              acc[2][j] += w0.z * xj; acc[3][j] += w0.w * xj;
              acc[4][j] += w1.x * xj; acc[5][j] += w1.y * xj;
              acc[6][j] += w1.z * xj; acc[7][j] += w1.w * xj;
            }
          }
        }
      }
      __syncthreads();
    }
  }
  // epilogue
  const int oh = oh0 + ohl;
  const int owb = owg * 10;
#pragma unroll
  for (int m = 0; m < 8; ++m) {
    const int co = co0 + cog * 8 + m;
    const float bv = b1[co];
    float* op = &feat[(((size_t)n * 512 + co) * 48 + oh) * 80 + owb];
#pragma unroll
    for (int j = 0; j < 10; j += 2) {
      float2 o2; o2.x = acc[m][j] + bv; o2.y = acc[m][j + 1] + bv;
      *(float2*)(op + j) = o2;
    }
  }
}

// ---------------- conv2: 1x1, feat -> deltas[b][pos][36] ----------------
__global__ __launch_bounds__(256) void conv2_k(const float* __restrict__ feat,
                                               const float* __restrict__ wb,
                                               const float* __restrict__ bb,
                                               float* __restrict__ deltas) {
  __shared__ float fs[16 * 128];
  __shared__ float wsb[16 * 36];
  const int tid = threadIdx.x;
  const int blk = blockIdx.x;   // 120
  const int b = blk / 30;
  const int pos0 = (blk % 30) * 128;
  const int pl = tid >> 1, cg = tid & 1;
  const int cbase = cg * 18;
  float acc[18];
#pragma unroll
  for (int j = 0; j < 18; ++j) acc[j] = 0.f;
  const float* fb = feat + (size_t)b * 512 * 3840;

  for (int c0 = 0; c0 < 512; c0 += 16) {
    for (int e = tid; e < 16 * 128; e += 256)
      fs[e] = fb[(size_t)(c0 + (e >> 7)) * 3840 + pos0 + (e & 127)];
    for (int e = tid; e < 16 * 36; e += 256) {
      int ci = e / 36, c = e - ci * 36;
      wsb[e] = wb[(size_t)c * 512 + c0 + ci];
    }
    __syncthreads();
    for (int ci = 0; ci < 16; ++ci) {
      float xv = fs[ci * 128 + pl];
#pragma unroll
      for (int j = 0; j < 18; ++j) acc[j] += xv * wsb[ci * 36 + cbase + j];
    }
    __syncthreads();
  }
  size_t o = ((size_t)b * 3840 + pos0 + pl) * 36 + cbase;
#pragma unroll
  for (int j = 0; j < 18; ++j) deltas[o + j] = acc[j] + bb[cbase + j];
}

// ---------------- conv3: 3x3 p1, channels 9..17 -> s[b][pos*9+a] ----------------
__global__ __launch_bounds__(256) void conv3_k(const float* __restrict__ feat,
                                               const float* __restrict__ wcg,
                                               const float* __restrict__ bc,
                                               float* __restrict__ s) {
  __shared__ float fs[16][3][84];   // [ci][ih][iw(-1..80)+1]
  __shared__ float wc[16][9][9];    // [ci][co][k]
  const int tid = threadIdx.x;
  const int oh = blockIdx.x;
  const int b = blockIdx.y;
  const int pos = tid % 80;
  const int cg = tid / 80;          // 0..3 (cg==3 idle for compute)
  float acc[3] = {0.f, 0.f, 0.f};
  const float* fb = feat + (size_t)b * 512 * 3840;

  for (int c0 = 0; c0 < 512; c0 += 16) {
    for (int e = tid; e < 16 * 246; e += 256) {
      int ci = e / 246;
      int r = e - ci * 246;
      int ihl = r / 82;
      int iw = r - ihl * 82 - 1;
      int gih = oh - 1 + ihl;
      float v = 0.f;
      if ((unsigned)gih < 48u && (unsigned)iw < 80u)
        v = fb[(size_t)(c0 + ci) * 3840 + gih * 80 + iw];
      fs[ci][ihl][iw + 1] = v;
    }
    for (int e = tid; e < 16 * 81; e += 256) {
      int ci = e / 81;
      int r = e - ci * 81;
      int co = r / 9;
      int k = r - co * 9;
      wc[ci][co][k] = wcg[((size_t)(9 + co) * 512 + c0 + ci) * 9 + k];
    }
    __syncthreads();
    if (cg < 3) {
      const int cb = cg * 3;
      for (int ci = 0; ci < 16; ++ci) {
#pragma unroll
        for (int kh = 0; kh < 3; ++kh) {
#pragma unroll
          for (int kw = 0; kw < 3; ++kw) {
            float xv = fs[ci][kh][pos + kw];
            acc[0] += xv * wc[ci][cb + 0][kh * 3 + kw];
            acc[1] += xv * wc[ci][cb + 1][kh * 3 + kw];
            acc[2] += xv * wc[ci][cb + 2][kh * 3 + kw];
          }
        }
      }
    }
    __syncthreads();
  }
  if (cg < 3) {
    const int cb = cg * 3;
    size_t o = (size_t)b * 34560 + ((size_t)oh * 80 + pos) * 9 + cb;
#pragma unroll
    for (int j = 0; j < 3; ++j) s[o + j] = acc[j] + bc[9 + cb + j];
  }
}

// ---------------- decode: anchors + deltas -> boxes, filtered score keys ----------------
__global__ __launch_bounds__(256) void decode_k(const float* __restrict__ deltas,
                                                const float* __restrict__ s,
                                                float* __restrict__ boxes,
                                                u64* __restrict__ keys) {
  const int g = blockIdx.x * 256 + threadIdx.x;  // < 138240 exactly
  const int b = g / 34560;
  const int i = g - b * 34560;
  const int pos = i / 9;
  const int a = i - pos * 9;
  const int h = pos / 80;
  const int w = pos - h * 80;
  const float gx = (float)(w * 32);
  const float gy = (float)(h * 32);
  const float aw = c_aw[a], ah = c_ah[a];
  const float x1a = 7.5f - 0.5f * (aw - 1.f);   // exact
  const float y1a = 7.5f - 0.5f * (ah - 1.f);   // exact
  const float ws_ = aw, hs_ = ah;               // x2-x1+1 exact
  const float cx = (gx + x1a) + 0.5f * ws_;     // exact
  const float cy = (gy + y1a) + 0.5f * hs_;     // exact

  const float* dp = &deltas[((size_t)b * 3840 + pos) * 36 + a * 4];
  const float d0 = dp[0], d1 = dp[1], d2 = dp[2], d3 = dp[3];
  const float pcx = __fadd_rn(__fmul_rn(d0, ws_), cx);
  const float pcy = __fadd_rn(__fmul_rn(d1, hs_), cy);
  const float pw = __fmul_rn(expf(d2), ws_);
  const float ph = __fmul_rn(expf(d3), hs_);
  float bx1 = __fsub_rn(pcx, __fmul_rn(0.5f, pw));
  float by1 = __fsub_rn(pcy, __fmul_rn(0.5f, ph));
  float bx2 = __fadd_rn(pcx, __fmul_rn(0.5f, pw));
  float by2 = __fadd_rn(pcy, __fmul_rn(0.5f, ph));
  bx1 = fminf(fmaxf(bx1, 0.f), 2559.f);
  by1 = fminf(fmaxf(by1, 0.f), 1535.f);
  bx2 = fminf(fmaxf(bx2, 0.f), 2559.f);
  by2 = fminf(fmaxf(by2, 0.f), 1535.f);
  const float bw = __fadd_rn(__fsub_rn(bx2, bx1), 1.f);
  const float bh = __fadd_rn(__fsub_rn(by2, by1), 1.f);
  float sc = s[g];
  if (!(bw >= 16.f && bh >= 16.f)) sc = -1e30f;

  float4 bo;
  bo.x = bx1; bo.y = by1; bo.z = bx2; bo.w = by2;
  *(float4*)&boxes[(size_t)g * 4] = bo;

  u32 sb = __float_as_uint(sc);
  u32 ou = (sb & 0x80000000u) ? ~sb : (sb | 0x80000000u);
  keys[g] = ((u64)ou << 32) | (u32)(~(u32)i);
}

// ---------------- select: exact rank-2000 key per batch via 6-pass radix histogram ----
__global__ __launch_bounds__(256) void select_k(const u64* __restrict__ keys,
                                                u64* __restrict__ Tout,
                                                int* __restrict__ cnt) {
  __shared__ u32 h[2048];
  __shared__ int s_bin;
  __shared__ u32 s_above;
  const int b = blockIdx.x;
  const int tid = threadIdx.x;
  const u64* kb = keys + (size_t)b * 34560;
  u64 prefix = 0, pmask = 0;
  int rank = 2000;

#pragma unroll 1
  for (int pass = 0; pass < 6; ++pass) {
    int shift = 53 - 11 * pass;
    if (shift < 0) shift = 0;
    // clear
#pragma unroll
    for (int q = 0; q < 8; ++q) h[tid + 256 * q] = 0;
    __syncthreads();
    // histogram of prefix-matching keys on 11 bits at `shift`
    for (int i = tid; i < 34560; i += 256) {
      u64 k = kb[i];
      if ((k & pmask) == prefix)
        atomicAdd(&h[(u32)((k >> shift) & 2047ull)], 1u);
    }
    __syncthreads();
    // suffix sum: h[i] = count with bin >= i
    for (int off = 1; off < 2048; off <<= 1) {
      u32 t[8];
#pragma unroll
      for (int q = 0; q < 8; ++q) {
        int i = tid + 256 * q;
        t[q] = h[i] + ((i + off < 2048) ? h[i + off] : 0u);
      }
      __syncthreads();
#pragma unroll
      for (int q = 0; q < 8; ++q) h[tid + 256 * q] = t[q];
      __syncthreads();
    }
    // find bin where suffix crosses rank
#pragma unroll
    for (int q = 0; q < 8; ++q) {
      int i = tid + 256 * q;
      u32 Si = h[i];
      u32 Sn = (i < 2047) ? h[i + 1] : 0u;
      if ((int)Si >= rank && (int)Sn < rank) { s_bin = i; s_above = Sn; }
    }
    __syncthreads();
    rank -= (int)s_above;
    prefix |= ((u64)(u32)s_bin) << shift;
    pmask |= (2047ull << shift);
    __syncthreads();
  }
  if (tid == 0) { Tout[b] = prefix; cnt[b] = 0; }
}

// ---------------- compact: keys >= T[b] (exactly 2000 per batch, unordered) ----------
__global__ __launch_bounds__(256) void compact_k(const u64* __restrict__ keys,
                                                 const u64* __restrict__ T,
                                                 int* __restrict__ cnt,
                                                 u64* __restrict__ sel) {
  const int g = blockIdx.x * 256 + threadIdx.x;  // < 138240 exactly
  const int b = g / 34560;
  u64 k = keys[g];
  if (k >= T[b]) {
    int p = atomicAdd(&cnt[b], 1);
    sel[(size_t)b * 2048 + p] = k;
  }
}

// ---------------- fused sort(2048) + greedy NMS per batch ----------------
__global__ __launch_bounds__(256) void nms2_k(const u64* __restrict__ sel,
                                              const float* __restrict__ boxes,
                                              float* __restrict__ out) {
  __shared__ u64 K[2048];
  __shared__ float bx1[2000], by1[2000], bx2[2000], by2[2000], ar[2000];
  __shared__ unsigned char val[2000];
  __shared__ int s_pick, s_cur, s_cnt;
  const int b = blockIdx.x;
  const int tid = threadIdx.x;

  for (int i = tid; i < 2048; i += 256)
    K[i] = (i < 2000) ? sel[(size_t)b * 2048 + i] : 0ull;
  __syncthreads();
  // bitonic sort descending
  for (int k2 = 2; k2 <= 2048; k2 <<= 1) {
    for (int j = k2 >> 1; j > 0; j >>= 1) {
      for (int i = tid; i < 2048; i += 256) {
        int l = i ^ j;
        if (l > i) {
          u64 a = K[i], c = K[l];
          bool up = ((i & k2) == 0);
          if (up ? (a < c) : (a > c)) { K[i] = c; K[l] = a; }
        }
      }
      __syncthreads();
    }
  }
  // extract boxes/validity in score order
  for (int i = tid; i < 2000; i += 256) {
    u64 key = K[i];
    u32 ou = (u32)(key >> 32);
    int idx = (int)(~(u32)key);
    u32 sb = (ou & 0x80000000u) ? (ou & 0x7FFFFFFFu) : ~ou;
    float sc = __uint_as_float(sb);
    const float4 bo = *(const float4*)&boxes[((size_t)b * 34560 + idx) * 4];
    bx1[i] = bo.x; by1[i] = bo.y; bx2[i] = bo.z; by2[i] = bo.w;
    ar[i] = __fmul_rn(__fadd_rn(__fsub_rn(bo.z, bo.x), 1.f),
                      __fadd_rn(__fsub_rn(bo.w, bo.y), 1.f));
    val[i] = (sc > -5e29f) ? 1 : 0;
  }
  if (tid == 0) { s_cur = 0; s_cnt = 0; }
  __syncthreads();

  for (int t = 0; t < 300; ++t) {
    if (tid == 0) {
      int c = s_cur;
      while (c < 2000 && !val[c]) ++c;
      if (c < 2000) { s_pick = c; s_cur = c + 1; s_cnt = t + 1; }
      else s_pick = -1;
    }
    __syncthreads();
    const int p = s_pick;
    if (p < 0) break;
    const float px1 = bx1[p], py1 = by1[p], px2 = bx2[p], py2 = by2[p], pa = ar[p];
    if (tid == 0) {
      float* row = out + ((size_t)b * 300 + t) * 5;
      row[0] = (float)b; row[1] = px1; row[2] = py1; row[3] = px2; row[4] = py2;
    }
    for (int jj = p + 1 + tid; jj < 2000; jj += 256) {
      if (val[jj]) {
        float iw = __fadd_rn(__fsub_rn(fminf(px2, bx2[jj]), fmaxf(px1, bx1[jj])), 1.f);
        iw = fmaxf(0.f, iw);
        float ih = __fadd_rn(__fsub_rn(fminf(py2, by2[jj]), fmaxf(py1, by1[jj])), 1.f);
        ih = fmaxf(0.f, ih);
        float inter = __fmul_rn(iw, ih);
        float denom = __fsub_rn(__fadd_rn(pa, ar[jj]), inter);
        float iou = __fdiv_rn(inter, denom);
        if (iou > 0.7f) val[jj] = 0;
      }
    }
    __syncthreads();
  }

  __syncthreads();
  const int cnt = s_cnt;
  for (int t = cnt + tid; t < 300; t += 256) {
    float* row = out + ((size_t)b * 300 + t) * 5;
    row[0] = (float)b; row[1] = 0.f; row[2] = 0.f; row[3] = 0.f; row[4] = 0.f;
  }
  if (tid == 0) out[6000 + b] = (float)cnt;
}

// ---------------- launcher ----------------
extern "C" void kernel_launch(void* const* d_in, const int* in_sizes, int n_in,
                              void* d_out, int out_size, void* d_ws, size_t ws_size,
                              hipStream_t stream) {
  const float* x  = (const float*)d_in[0];
  const float* w1 = (const float*)d_in[1];
  const float* b1 = (const float*)d_in[2];
  const float* wb = (const float*)d_in[3];
  const float* bb = (const float*)d_in[4];
  const float* wc = (const float*)d_in[5];
  const float* bc = (const float*)d_in[6];
  float* out = (float*)d_out;
  char* ws = (char*)d_ws;

  float* feat   = (float*)(ws + 0);           // 31,457,280 B
  float* wt     = (float*)(ws + 31457280);    //  9,437,184 B
  float* deltas = (float*)(ws + 40894464);    //  2,211,840 B
  float* s      = (float*)(ws + 43106304);    //    552,960 B
  float* boxes  = (float*)(ws + 43659264);    //  2,211,840 B
  u64*   keys   = (u64*)  (ws + 45871104);    //  1,105,920 B
  u64*   T      = (u64*)  (ws + 46977024);    //         32 B
  int*   cnt    = (int*)  (ws + 46977056);    //         32 B
  u64*   sel    = (u64*)  (ws + 46977088);    //     65,536 B

  hipLaunchKernelGGL(transpose_k, dim3(576), dim3(256), 0, stream, w1, wt);
  hipLaunchKernelGGL(conv1_k, dim3(8, 12, 4), dim3(256), 0, stream, x, wt, b1, feat);
  hipLaunchKernelGGL(conv2_k, dim3(120), dim3(256), 0, stream, feat, wb, bb, deltas);
  hipLaunchKernelGGL(conv3_k, dim3(48, 4), dim3(256), 0, stream, feat, wc, bc, s);
  hipLaunchKernelGGL(decode_k, dim3(540), dim3(256), 0, stream, deltas, s, boxes, keys);
  hipLaunchKernelGGL(select_k, dim3(4), dim3(256), 0, stream, keys, T, cnt);
  hipLaunchKernelGGL(compact_k, dim3(540), dim3(256), 0, stream, keys, T, cnt, sel);
  hipLaunchKernelGGL(nms2_k, dim3(4), dim3(256), 0, stream, sel, boxes, out);
}

// Round 6
// 2435.835 us; speedup vs baseline: 1.2440x; 1.2306x over previous
//
#include <hip/hip_runtime.h>
#include <stdint.h>

typedef unsigned long long u64;
typedef unsigned int u32;

// anchor (w,h) per a = ratio_idx*3 + scale_idx ; ratios (.5,1,2), scales (8,16,32)
__constant__ float c_aw[9] = {184.f,368.f,736.f,128.f,256.f,512.f, 88.f,176.f,352.f};
__constant__ float c_ah[9] = { 96.f,192.f,384.f,128.f,256.f,512.f,176.f,352.f,704.f};

// ---------------- w1 transpose: w1[co][ci*9+k] -> wt[(ci*9+k)][co] ----------------
__global__ __launch_bounds__(256) void transpose_k(const float* __restrict__ w1,
                                                   float* __restrict__ wt) {
  __shared__ float t[64][65];
  const int bx = blockIdx.x & 7;    // co block (512/64)
  const int by = blockIdx.x >> 3;   // q block (4608/64)
  const int tid = threadIdx.x;
  const int co0 = bx * 64, q0 = by * 64;
  for (int e = tid; e < 4096; e += 256) {
    int co_l = e >> 6, q_l = e & 63;
    t[q_l][co_l] = w1[(size_t)(co0 + co_l) * 4608 + q0 + q_l];
  }
  __syncthreads();
  for (int e = tid; e < 4096; e += 256) {
    int q_l = e >> 6, co_l = e & 63;
    wt[(size_t)(q0 + q_l) * 512 + co0 + co_l] = t[q_l][co_l];
  }
}

// ---------------- conv1: x(4,512,96,160) * w(512,512,3,3) s2 p1 -> feat(4,512,48,80)
// block tile: 64co x 2oh x 80ow (grid 8x24x4 = 768 = 3 blocks/CU exactly).
// thread tile: 8co x 5ow. accumulation order (c0 chunk of 8, ci, kh, kw) bitwise
// matches the passing kernels.
__global__ __launch_bounds__(256, 3) void conv1_k(const float* __restrict__ x,
                                                  const float* __restrict__ wt,
                                                  const float* __restrict__ b1,
                                                  float* __restrict__ feat) {
  __shared__ float xs[8 * 5 * 164];   // [ci][ih(5)][iw(161) pad 164] = 26240 B
  __shared__ float ws2[8 * 9 * 64];   // [ci*9+k][co(64)] = 18432 B
  const int tid = threadIdx.x;
  const int owg = tid & 15;           // 16 groups of 5 ow
  const int ohl = (tid >> 4) & 1;     // 2 oh rows
  const int cog = tid >> 5;           // 8 groups of 8 co
  const int n = blockIdx.z;
  const int co0 = blockIdx.x * 64;
  const int oh0 = blockIdx.y * 2;
  const int ih_base = 2 * oh0 - 1;

  float acc[8][5];
#pragma unroll
  for (int m = 0; m < 8; ++m)
#pragma unroll
    for (int j = 0; j < 5; ++j) acc[m][j] = 0.f;

  const float* xb = x + (size_t)n * 512 * 96 * 160;

  for (int c0 = 0; c0 < 512; c0 += 8) {
    // stage x: 8 ci x 5 rows x 161 cols (col c <-> iw = c-1), stride-1 writes
    for (int e2 = tid; e2 < 805; e2 += 256) {
      int ih = e2 / 161;
      int c = e2 - ih * 161;
      int gih = ih_base + ih;
      int giw = c - 1;
      bool ok = ((unsigned)gih < 96u) && ((unsigned)giw < 160u);
      const float* gp = xb + ((size_t)c0 * 96 + gih) * 160 + giw;
      float* lp = &xs[ih * 164 + c];
#pragma unroll
      for (int ci = 0; ci < 8; ++ci)
        lp[ci * 820] = ok ? gp[(size_t)ci * 15360] : 0.f;   // 820 = 5*164
    }
    // stage w: 8 ci x 9 k x 64 co, stride-1 writes, coalesced reads
    for (int e = tid; e < 4608; e += 256)
      ws2[e] = wt[((size_t)c0 * 9 + (e >> 6)) * 512 + co0 + (e & 63)];
    __syncthreads();

    for (int ci = 0; ci < 8; ++ci) {
      const float* xrow = &xs[(ci * 5 + 2 * ohl) * 164 + owg * 10];
      const float* wrow = &ws2[ci * 9 * 64 + cog * 8];
#pragma unroll
      for (int kh = 0; kh < 3; ++kh) {
        float xv[12];
        const float* xr = xrow + kh * 164;
#pragma unroll
        for (int t2 = 0; t2 < 6; ++t2) {          // 8B-aligned b64 LDS reads
          float2 t = *(const float2*)(xr + 2 * t2);
          xv[2 * t2] = t.x; xv[2 * t2 + 1] = t.y;
        }
#pragma unroll
        for (int kw = 0; kw < 3; ++kw) {
          const float4 w0 = *(const float4*)&wrow[(kh * 3 + kw) * 64];
          const float4 w1 = *(const float4*)&wrow[(kh * 3 + kw) * 64 + 4];
#pragma unroll
          for (int j = 0; j < 5; ++j) {
            const float xj = xv[kw + 2 * j];
            acc[0][j] += w0.x * xj; acc[1][j] += w0.y * xj;
            acc[2][j] += w0.z * xj; acc[3][j] += w0.w * xj;
            acc[4][j] += w1.x * xj; acc[5][j] += w1.y * xj;
            acc[6][j] += w1.z * xj; acc[7][j] += w1.w * xj;
          }
        }
      }
    }
    __syncthreads();
  }
  // epilogue
  const int oh = oh0 + ohl;
  const int owb = owg * 5;
#pragma unroll
  for (int m = 0; m < 8; ++m) {
    const int co = co0 + cog * 8 + m;
    const float bv = b1[co];
    float* op = &feat[(((size_t)n * 512 + co) * 48 + oh) * 80 + owb];
#pragma unroll
    for (int j = 0; j < 5; ++j) op[j] = acc[m][j] + bv;
  }
}

// ---------------- conv2: 1x1, feat -> deltas[b][pos][36] ----------------
__global__ __launch_bounds__(256) void conv2_k(const float* __restrict__ feat,
                                               const float* __restrict__ wb,
                                               const float* __restrict__ bb,
                                               float* __restrict__ deltas) {
  __shared__ float fs[16 * 128];
  __shared__ float wsb[16 * 36];
  const int tid = threadIdx.x;
  const int blk = blockIdx.x;   // 120
  const int b = blk / 30;
  const int pos0 = (blk % 30) * 128;
  const int pl = tid >> 1, cg = tid & 1;
  const int cbase = cg * 18;
  float acc[18];
#pragma unroll
  for (int j = 0; j < 18; ++j) acc[j] = 0.f;
  const float* fb = feat + (size_t)b * 512 * 3840;

  for (int c0 = 0; c0 < 512; c0 += 16) {
    for (int e = tid; e < 16 * 128; e += 256)
      fs[e] = fb[(size_t)(c0 + (e >> 7)) * 3840 + pos0 + (e & 127)];
    for (int e = tid; e < 16 * 36; e += 256) {
      int ci = e / 36, c = e - ci * 36;
      wsb[e] = wb[(size_t)c * 512 + c0 + ci];
    }
    __syncthreads();
    for (int ci = 0; ci < 16; ++ci) {
      float xv = fs[ci * 128 + pl];
#pragma unroll
      for (int j = 0; j < 18; ++j) acc[j] += xv * wsb[ci * 36 + cbase + j];
    }
    __syncthreads();
  }
  size_t o = ((size_t)b * 3840 + pos0 + pl) * 36 + cbase;
#pragma unroll
  for (int j = 0; j < 18; ++j) deltas[o + j] = acc[j] + bb[cbase + j];
}

// ---------------- conv3: 3x3 p1, channels 9..17 -> s[b][pos*9+a] ----------------
__global__ __launch_bounds__(256) void conv3_k(const float* __restrict__ feat,
                                               const float* __restrict__ wcg,
                                               const float* __restrict__ bc,
                                               float* __restrict__ s) {
  __shared__ float fs[16][3][84];   // [ci][ih][iw(-1..80)+1]
  __shared__ float wc[16][9][9];    // [ci][co][k]
  const int tid = threadIdx.x;
  const int oh = blockIdx.x;
  const int b = blockIdx.y;
  const int pos = tid % 80;
  const int cg = tid / 80;          // 0..3 (cg==3 idle for compute)
  float acc[3] = {0.f, 0.f, 0.f};
  const float* fb = feat + (size_t)b * 512 * 3840;

  for (int c0 = 0; c0 < 512; c0 += 16) {
    for (int e = tid; e < 16 * 246; e += 256) {
      int ci = e / 246;
      int r = e - ci * 246;
      int ihl = r / 82;
      int iw = r - ihl * 82 - 1;
      int gih = oh - 1 + ihl;
      float v = 0.f;
      if ((unsigned)gih < 48u && (unsigned)iw < 80u)
        v = fb[(size_t)(c0 + ci) * 3840 + gih * 80 + iw];
      fs[ci][ihl][iw + 1] = v;
    }
    for (int e = tid; e < 16 * 81; e += 256) {
      int ci = e / 81;
      int r = e - ci * 81;
      int co = r / 9;
      int k = r - co * 9;
      wc[ci][co][k] = wcg[((size_t)(9 + co) * 512 + c0 + ci) * 9 + k];
    }
    __syncthreads();
    if (cg < 3) {
      const int cb = cg * 3;
      for (int ci = 0; ci < 16; ++ci) {
#pragma unroll
        for (int kh = 0; kh < 3; ++kh) {
#pragma unroll
          for (int kw = 0; kw < 3; ++kw) {
            float xv = fs[ci][kh][pos + kw];
            acc[0] += xv * wc[ci][cb + 0][kh * 3 + kw];
            acc[1] += xv * wc[ci][cb + 1][kh * 3 + kw];
            acc[2] += xv * wc[ci][cb + 2][kh * 3 + kw];
          }
        }
      }
    }
    __syncthreads();
  }
  if (cg < 3) {
    const int cb = cg * 3;
    size_t o = (size_t)b * 34560 + ((size_t)oh * 80 + pos) * 9 + cb;
#pragma unroll
    for (int j = 0; j < 3; ++j) s[o + j] = acc[j] + bc[9 + cb + j];
  }
}

// ---------------- decode: anchors + deltas -> boxes, filtered score keys ----------------
__global__ __launch_bounds__(256) void decode_k(const float* __restrict__ deltas,
                                                const float* __restrict__ s,
                                                float* __restrict__ boxes,
                                                u64* __restrict__ keys) {
  const int g = blockIdx.x * 256 + threadIdx.x;  // < 138240 exactly
  const int b = g / 34560;
  const int i = g - b * 34560;
  const int pos = i / 9;
  const int a = i - pos * 9;
  const int h = pos / 80;
  const int w = pos - h * 80;
  const float gx = (float)(w * 32);
  const float gy = (float)(h * 32);
  const float aw = c_aw[a], ah = c_ah[a];
  const float x1a = 7.5f - 0.5f * (aw - 1.f);   // exact
  const float y1a = 7.5f - 0.5f * (ah - 1.f);   // exact
  const float ws_ = aw, hs_ = ah;               // x2-x1+1 exact
  const float cx = (gx + x1a) + 0.5f * ws_;     // exact
  const float cy = (gy + y1a) + 0.5f * hs_;     // exact

  const float* dp = &deltas[((size_t)b * 3840 + pos) * 36 + a * 4];
  const float d0 = dp[0], d1 = dp[1], d2 = dp[2], d3 = dp[3];
  const float pcx = __fadd_rn(__fmul_rn(d0, ws_), cx);
  const float pcy = __fadd_rn(__fmul_rn(d1, hs_), cy);
  const float pw = __fmul_rn(expf(d2), ws_);
  const float ph = __fmul_rn(expf(d3), hs_);
  float bx1 = __fsub_rn(pcx, __fmul_rn(0.5f, pw));
  float by1 = __fsub_rn(pcy, __fmul_rn(0.5f, ph));
  float bx2 = __fadd_rn(pcx, __fmul_rn(0.5f, pw));
  float by2 = __fadd_rn(pcy, __fmul_rn(0.5f, ph));
  bx1 = fminf(fmaxf(bx1, 0.f), 2559.f);
  by1 = fminf(fmaxf(by1, 0.f), 1535.f);
  bx2 = fminf(fmaxf(bx2, 0.f), 2559.f);
  by2 = fminf(fmaxf(by2, 0.f), 1535.f);
  const float bw = __fadd_rn(__fsub_rn(bx2, bx1), 1.f);
  const float bh = __fadd_rn(__fsub_rn(by2, by1), 1.f);
  float sc = s[g];
  if (!(bw >= 16.f && bh >= 16.f)) sc = -1e30f;

  float4 bo;
  bo.x = bx1; bo.y = by1; bo.z = bx2; bo.w = by2;
  *(float4*)&boxes[(size_t)g * 4] = bo;

  u32 sb = __float_as_uint(sc);
  u32 ou = (sb & 0x80000000u) ? ~sb : (sb | 0x80000000u);
  keys[g] = ((u64)ou << 32) | (u32)(~(u32)i);
}

// ---------------- select: exact rank-2000 key per batch via 6-pass radix histogram ----
__global__ __launch_bounds__(256) void select_k(const u64* __restrict__ keys,
                                                u64* __restrict__ Tout,
                                                int* __restrict__ cnt) {
  __shared__ u32 h[2048];
  __shared__ int s_bin;
  __shared__ u32 s_above;
  const int b = blockIdx.x;
  const int tid = threadIdx.x;
  const u64* kb = keys + (size_t)b * 34560;
  u64 prefix = 0, pmask = 0;
  int rank = 2000;

#pragma unroll 1
  for (int pass = 0; pass < 6; ++pass) {
    int shift = 53 - 11 * pass;
    if (shift < 0) shift = 0;
    // clear
#pragma unroll
    for (int q = 0; q < 8; ++q) h[tid + 256 * q] = 0;
    __syncthreads();
    // histogram of prefix-matching keys on 11 bits at `shift`
    for (int i = tid; i < 34560; i += 256) {
      u64 k = kb[i];
      if ((k & pmask) == prefix)
        atomicAdd(&h[(u32)((k >> shift) & 2047ull)], 1u);
    }
    __syncthreads();
    // suffix sum: h[i] = count with bin >= i
    for (int off = 1; off < 2048; off <<= 1) {
      u32 t[8];
#pragma unroll
      for (int q = 0; q < 8; ++q) {
        int i = tid + 256 * q;
        t[q] = h[i] + ((i + off < 2048) ? h[i + off] : 0u);
      }
      __syncthreads();
#pragma unroll
      for (int q = 0; q < 8; ++q) h[tid + 256 * q] = t[q];
      __syncthreads();
    }
    // find bin where suffix crosses rank
#pragma unroll
    for (int q = 0; q < 8; ++q) {
      int i = tid + 256 * q;
      u32 Si = h[i];
      u32 Sn = (i < 2047) ? h[i + 1] : 0u;
      if ((int)Si >= rank && (int)Sn < rank) { s_bin = i; s_above = Sn; }
    }
    __syncthreads();
    rank -= (int)s_above;
    prefix |= ((u64)(u32)s_bin) << shift;
    pmask |= (2047ull << shift);
    __syncthreads();
  }
  if (tid == 0) { Tout[b] = prefix; cnt[b] = 0; }
}

// ---------------- compact: keys >= T[b] (exactly 2000 per batch, unordered) ----------
__global__ __launch_bounds__(256) void compact_k(const u64* __restrict__ keys,
                                                 const u64* __restrict__ T,
                                                 int* __restrict__ cnt,
                                                 u64* __restrict__ sel) {
  const int g = blockIdx.x * 256 + threadIdx.x;  // < 138240 exactly
  const int b = g / 34560;
  u64 k = keys[g];
  if (k >= T[b]) {
    int p = atomicAdd(&cnt[b], 1);
    sel[(size_t)b * 2048 + p] = k;
  }
}

// ---------------- fused sort(2048) + greedy NMS per batch ----------------
__global__ __launch_bounds__(256) void nms2_k(const u64* __restrict__ sel,
                                              const float* __restrict__ boxes,
                                              float* __restrict__ out) {
  __shared__ u64 K[2048];
  __shared__ float bx1[2000], by1[2000], bx2[2000], by2[2000], ar[2000];
  __shared__ unsigned char val[2000];
  __shared__ int s_pick, s_cur, s_cnt;
  const int b = blockIdx.x;
  const int tid = threadIdx.x;

  for (int i = tid; i < 2048; i += 256)
    K[i] = (i < 2000) ? sel[(size_t)b * 2048 + i] : 0ull;
  __syncthreads();
  // bitonic sort descending
  for (int k2 = 2; k2 <= 2048; k2 <<= 1) {
    for (int j = k2 >> 1; j > 0; j >>= 1) {
      for (int i = tid; i < 2048; i += 256) {
        int l = i ^ j;
        if (l > i) {
          u64 a = K[i], c = K[l];
          bool up = ((i & k2) == 0);
          if (up ? (a < c) : (a > c)) { K[i] = c; K[l] = a; }
        }
      }
      __syncthreads();
    }
  }
  // extract boxes/validity in score order
  for (int i = tid; i < 2000; i += 256) {
    u64 key = K[i];
    u32 ou = (u32)(key >> 32);
    int idx = (int)(~(u32)key);
    u32 sb = (ou & 0x80000000u) ? (ou & 0x7FFFFFFFu) : ~ou;
    float sc = __uint_as_float(sb);
    const float4 bo = *(const float4*)&boxes[((size_t)b * 34560 + idx) * 4];
    bx1[i] = bo.x; by1[i] = bo.y; bx2[i] = bo.z; by2[i] = bo.w;
    ar[i] = __fmul_rn(__fadd_rn(__fsub_rn(bo.z, bo.x), 1.f),
                      __fadd_rn(__fsub_rn(bo.w, bo.y), 1.f));
    val[i] = (sc > -5e29f) ? 1 : 0;
  }
  if (tid == 0) { s_cur = 0; s_cnt = 0; }
  __syncthreads();

  for (int t = 0; t < 300; ++t) {
    if (tid == 0) {
      int c = s_cur;
      while (c < 2000 && !val[c]) ++c;
      if (c < 2000) { s_pick = c; s_cur = c + 1; s_cnt = t + 1; }
      else s_pick = -1;
    }
    __syncthreads();
    const int p = s_pick;
    if (p < 0) break;
    const float px1 = bx1[p], py1 = by1[p], px2 = bx2[p], py2 = by2[p], pa = ar[p];
    if (tid == 0) {
      float* row = out + ((size_t)b * 300 + t) * 5;
      row[0] = (float)b; row[1] = px1; row[2] = py1; row[3] = px2; row[4] = py2;
    }
    for (int jj = p + 1 + tid; jj < 2000; jj += 256) {
      if (val[jj]) {
        float iw = __fadd_rn(__fsub_rn(fminf(px2, bx2[jj]), fmaxf(px1, bx1[jj])), 1.f);
        iw = fmaxf(0.f, iw);
        float ih = __fadd_rn(__fsub_rn(fminf(py2, by2[jj]), fmaxf(py1, by1[jj])), 1.f);
        ih = fmaxf(0.f, ih);
        float inter = __fmul_rn(iw, ih);
        float denom = __fsub_rn(__fadd_rn(pa, ar[jj]), inter);
        float iou = __fdiv_rn(inter, denom);
        if (iou > 0.7f) val[jj] = 0;
      }
    }
    __syncthreads();
  }

  __syncthreads();
  const int cnt = s_cnt;
  for (int t = cnt + tid; t < 300; t += 256) {
    float* row = out + ((size_t)b * 300 + t) * 5;
    row[0] = (float)b; row[1] = 0.f; row[2] = 0.f; row[3] = 0.f; row[4] = 0.f;
  }
  if (tid == 0) out[6000 + b] = (float)cnt;
}

// ---------------- launcher ----------------
extern "C" void kernel_launch(void* const* d_in, const int* in_sizes, int n_in,
                              void* d_out, int out_size, void* d_ws, size_t ws_size,
                              hipStream_t stream) {
  const float* x  = (const float*)d_in[0];
  const float* w1 = (const float*)d_in[1];
  const float* b1 = (const float*)d_in[2];
  const float* wb = (const float*)d_in[3];
  const float* bb = (const float*)d_in[4];
  const float* wc = (const float*)d_in[5];
  const float* bc = (const float*)d_in[6];
  float* out = (float*)d_out;
  char* ws = (char*)d_ws;

  float* feat   = (float*)(ws + 0);           // 31,457,280 B
  float* wt     = (float*)(ws + 31457280);    //  9,437,184 B
  float* deltas = (float*)(ws + 40894464);    //  2,211,840 B
  float* s      = (float*)(ws + 43106304);    //    552,960 B
  float* boxes  = (float*)(ws + 43659264);    //  2,211,840 B
  u64*   keys   = (u64*)  (ws + 45871104);    //  1,105,920 B
  u64*   T      = (u64*)  (ws + 46977024);    //         32 B
  int*   cnt    = (int*)  (ws + 46977056);    //         32 B
  u64*   sel    = (u64*)  (ws + 46977088);    //     65,536 B

  hipLaunchKernelGGL(transpose_k, dim3(576), dim3(256), 0, stream, w1, wt);
  hipLaunchKernelGGL(conv1_k, dim3(8, 24, 4), dim3(256), 0, stream, x, wt, b1, feat);
  hipLaunchKernelGGL(conv2_k, dim3(120), dim3(256), 0, stream, feat, wb, bb, deltas);
  hipLaunchKernelGGL(conv3_k, dim3(48, 4), dim3(256), 0, stream, feat, wc, bc, s);
  hipLaunchKernelGGL(decode_k, dim3(540), dim3(256), 0, stream, deltas, s, boxes, keys);
  hipLaunchKernelGGL(select_k, dim3(4), dim3(256), 0, stream, keys, T, cnt);
  hipLaunchKernelGGL(compact_k, dim3(540), dim3(256), 0, stream, keys, T, cnt, sel);
  hipLaunchKernelGGL(nms2_k, dim3(4), dim3(256), 0, stream, sel, boxes, out);
}

// Round 7
// 1783.905 us; speedup vs baseline: 1.6986x; 1.3655x over previous
//
#include <hip/hip_runtime.h>
#include <stdint.h>

typedef unsigned long long u64;
typedef unsigned int u32;

// anchor (w,h) per a = ratio_idx*3 + scale_idx ; ratios (.5,1,2), scales (8,16,32)
__constant__ float c_aw[9] = {184.f,368.f,736.f,128.f,256.f,512.f, 88.f,176.f,352.f};
__constant__ float c_ah[9] = { 96.f,192.f,384.f,128.f,256.f,512.f,176.f,352.f,704.f};

// -------- w1 reorder: w1[co][ci*9+k] -> wt2[g][ci][k][m], co = g*8+m ----------
__global__ __launch_bounds__(256) void transpose_k(const float* __restrict__ w1,
                                                   float* __restrict__ wt2) {
  int e = blockIdx.x * 256 + threadIdx.x;   // < 2359296 exactly
  int m = e & 7;
  int t = e >> 3;
  int k = t % 9;
  int r = t / 9;          // g*512 + ci
  int ci = r & 511;
  int g = r >> 9;
  wt2[e] = w1[(size_t)(g * 8 + m) * 4608 + ci * 9 + k];
}

// ---------------- conv1: x(4,512,96,160) * w s2 p1 -> feat(4,512,48,80)
// block tile: 32co x 4oh x 80ow, 4 waves, wave = one co-group of 8 (scalar weights).
// lane: owg = lane&15 (5 ow each), ohl = lane>>4 (4 oh rows).
// grid 16x12x4 = 768 = 3 blocks/CU. accumulation order (c0 by 8, ci, kh, kw) bitwise
// matches all passing rounds.
__global__ __launch_bounds__(256, 3) void conv1_k(const float* __restrict__ x,
                                                  const float* __restrict__ wt2,
                                                  const float* __restrict__ b1,
                                                  float* __restrict__ feat) {
  __shared__ float xs[8 * 9 * 164];   // [ci][ih(9)][iw(161) pad 164] = 47232 B
  const int tid = threadIdx.x;
  const int lane = tid & 63;
  const int wv = __builtin_amdgcn_readfirstlane(tid >> 6);   // wave id 0..3 (SGPR)
  const int owg = lane & 15;          // 16 groups of 5 ow
  const int ohl = lane >> 4;          // 0..3
  const int n = blockIdx.z;
  const int gg = blockIdx.x * 4 + wv; // global co-group, co = gg*8+m
  const int oh0 = blockIdx.y * 4;
  const int ih_base = 2 * oh0 - 1;

  float acc[8][5];
#pragma unroll
  for (int m = 0; m < 8; ++m)
#pragma unroll
    for (int j = 0; j < 5; ++j) acc[m][j] = 0.f;

  const float* xb = x + (size_t)n * 512 * 96 * 160;
  const float* wgb = wt2 + (size_t)gg * 512 * 72;   // [ci][k(9)][m(8)]

  for (int c0 = 0; c0 < 512; c0 += 8) {
    // stage x: 8 ci x 9 rows x 161 cols (col c <-> iw = c-1), stride-1 writes
    for (int e2 = tid; e2 < 1449; e2 += 256) {
      int ih = e2 / 161;
      int c = e2 - ih * 161;
      int gih = ih_base + ih;
      int giw = c - 1;
      bool ok = ((unsigned)gih < 96u) && ((unsigned)giw < 160u);
      const float* gp = xb + ((size_t)c0 * 96 + gih) * 160 + giw;
      float* lp = &xs[ih * 164 + c];
#pragma unroll
      for (int ci = 0; ci < 8; ++ci)
        lp[ci * 1476] = ok ? gp[(size_t)ci * 15360] : 0.f;   // 1476 = 9*164
    }
    __syncthreads();

    for (int ci = 0; ci < 8; ++ci) {
      const float* wp = wgb + (size_t)(c0 + ci) * 72;   // wave-uniform -> s_load
      const float* xrow = &xs[(ci * 9 + 2 * ohl) * 164 + owg * 10];
#pragma unroll
      for (int kh = 0; kh < 3; ++kh) {
        float xv[12];
        const float* xr = xrow + kh * 164;
#pragma unroll
        for (int t2 = 0; t2 < 6; ++t2) {          // 8B-aligned b64 LDS reads
          float2 t = *(const float2*)(xr + 2 * t2);
          xv[2 * t2] = t.x; xv[2 * t2 + 1] = t.y;
        }
#pragma unroll
        for (int kw = 0; kw < 3; ++kw) {
          const float* wk = wp + (kh * 3 + kw) * 8;
#pragma unroll
          for (int j = 0; j < 5; ++j) {
            const float xj = xv[kw + 2 * j];
            acc[0][j] += wk[0] * xj; acc[1][j] += wk[1] * xj;
            acc[2][j] += wk[2] * xj; acc[3][j] += wk[3] * xj;
            acc[4][j] += wk[4] * xj; acc[5][j] += wk[5] * xj;
            acc[6][j] += wk[6] * xj; acc[7][j] += wk[7] * xj;
          }
        }
      }
    }
    __syncthreads();
  }
  // epilogue
  const int oh = oh0 + ohl;
  const int owb = owg * 5;
#pragma unroll
  for (int m = 0; m < 8; ++m) {
    const int co = gg * 8 + m;
    const float bv = b1[co];
    float* op = &feat[(((size_t)n * 512 + co) * 48 + oh) * 80 + owb];
#pragma unroll
    for (int j = 0; j < 5; ++j) op[j] = acc[m][j] + bv;
  }
}

// ---------------- fused heads: blocks [0,120) = conv2 (1x1 bbox), [120,312) = conv3 (3x3 cls)
__global__ __launch_bounds__(256) void heads_k(const float* __restrict__ feat,
                                               const float* __restrict__ wb,
                                               const float* __restrict__ bb,
                                               const float* __restrict__ wcg,
                                               const float* __restrict__ bc,
                                               float* __restrict__ deltas,
                                               float* __restrict__ s) {
  __shared__ float smem[5328];
  const int tid = threadIdx.x;

  if (blockIdx.x < 120) {
    // ---- conv2: 1x1, feat -> deltas[b][pos][36] ----
    float* fs  = smem;          // 16*128
    float* wsb = smem + 2048;   // 16*36
    const int blk = blockIdx.x;
    const int b = blk / 30;
    const int pos0 = (blk % 30) * 128;
    const int pl = tid >> 1, cg = tid & 1;
    const int cbase = cg * 18;
    float acc[18];
#pragma unroll
    for (int j = 0; j < 18; ++j) acc[j] = 0.f;
    const float* fb = feat + (size_t)b * 512 * 3840;

    for (int c0 = 0; c0 < 512; c0 += 16) {
      for (int e = tid; e < 16 * 128; e += 256)
        fs[e] = fb[(size_t)(c0 + (e >> 7)) * 3840 + pos0 + (e & 127)];
      for (int e = tid; e < 16 * 36; e += 256) {
        int ci = e / 36, c = e - ci * 36;
        wsb[e] = wb[(size_t)c * 512 + c0 + ci];
      }
      __syncthreads();
      for (int ci = 0; ci < 16; ++ci) {
        float xv = fs[ci * 128 + pl];
#pragma unroll
        for (int j = 0; j < 18; ++j) acc[j] += xv * wsb[ci * 36 + cbase + j];
      }
      __syncthreads();
    }
    size_t o = ((size_t)b * 3840 + pos0 + pl) * 36 + cbase;
#pragma unroll
    for (int j = 0; j < 18; ++j) deltas[o + j] = acc[j] + bb[cbase + j];
  } else {
    // ---- conv3: 3x3 p1, cls channels 9..17 -> s[b][pos*9+a] ----
    float (*fs)[3][84] = (float(*)[3][84])smem;           // 16*3*84 = 4032
    float (*wc)[9][9]  = (float(*)[9][9])(smem + 4032);   // 16*81 = 1296
    const int bid2 = blockIdx.x - 120;
    const int oh = bid2 % 48;
    const int b = bid2 / 48;
    const int pos = tid % 80;
    const int cg = tid / 80;          // 0..3 (cg==3 idle for compute)
    float acc[3] = {0.f, 0.f, 0.f};
    const float* fb = feat + (size_t)b * 512 * 3840;

    for (int c0 = 0; c0 < 512; c0 += 16) {
      for (int e = tid; e < 16 * 246; e += 256) {
        int ci = e / 246;
        int r = e - ci * 246;
        int ihl = r / 82;
        int iw = r - ihl * 82 - 1;
        int gih = oh - 1 + ihl;
        float v = 0.f;
        if ((unsigned)gih < 48u && (unsigned)iw < 80u)
          v = fb[(size_t)(c0 + ci) * 3840 + gih * 80 + iw];
        fs[ci][ihl][iw + 1] = v;
      }
      for (int e = tid; e < 16 * 81; e += 256) {
        int ci = e / 81;
        int r = e - ci * 81;
        int co = r / 9;
        int k = r - co * 9;
        wc[ci][co][k] = wcg[((size_t)(9 + co) * 512 + c0 + ci) * 9 + k];
      }
      __syncthreads();
      if (cg < 3) {
        const int cb = cg * 3;
        for (int ci = 0; ci < 16; ++ci) {
#pragma unroll
          for (int kh = 0; kh < 3; ++kh) {
#pragma unroll
            for (int kw = 0; kw < 3; ++kw) {
              float xv = fs[ci][kh][pos + kw];
              acc[0] += xv * wc[ci][cb + 0][kh * 3 + kw];
              acc[1] += xv * wc[ci][cb + 1][kh * 3 + kw];
              acc[2] += xv * wc[ci][cb + 2][kh * 3 + kw];
            }
          }
        }
      }
      __syncthreads();
    }
    if (cg < 3) {
      const int cb = cg * 3;
      size_t o = (size_t)b * 34560 + ((size_t)oh * 80 + pos) * 9 + cb;
#pragma unroll
      for (int j = 0; j < 3; ++j) s[o + j] = acc[j] + bc[9 + cb + j];
    }
  }
}

// ---------------- decode: anchors + deltas -> boxes, filtered score keys ----------------
__global__ __launch_bounds__(256) void decode_k(const float* __restrict__ deltas,
                                                const float* __restrict__ s,
                                                float* __restrict__ boxes,
                                                u64* __restrict__ keys) {
  const int g = blockIdx.x * 256 + threadIdx.x;  // < 138240 exactly
  const int b = g / 34560;
  const int i = g - b * 34560;
  const int pos = i / 9;
  const int a = i - pos * 9;
  const int h = pos / 80;
  const int w = pos - h * 80;
  const float gx = (float)(w * 32);
  const float gy = (float)(h * 32);
  const float aw = c_aw[a], ah = c_ah[a];
  const float x1a = 7.5f - 0.5f * (aw - 1.f);   // exact
  const float y1a = 7.5f - 0.5f * (ah - 1.f);   // exact
  const float ws_ = aw, hs_ = ah;               // x2-x1+1 exact
  const float cx = (gx + x1a) + 0.5f * ws_;     // exact
  const float cy = (gy + y1a) + 0.5f * hs_;     // exact

  const float* dp = &deltas[((size_t)b * 3840 + pos) * 36 + a * 4];
  const float d0 = dp[0], d1 = dp[1], d2 = dp[2], d3 = dp[3];
  const float pcx = __fadd_rn(__fmul_rn(d0, ws_), cx);
  const float pcy = __fadd_rn(__fmul_rn(d1, hs_), cy);
  const float pw = __fmul_rn(expf(d2), ws_);
  const float ph = __fmul_rn(expf(d3), hs_);
  float bx1 = __fsub_rn(pcx, __fmul_rn(0.5f, pw));
  float by1 = __fsub_rn(pcy, __fmul_rn(0.5f, ph));
  float bx2 = __fadd_rn(pcx, __fmul_rn(0.5f, pw));
  float by2 = __fadd_rn(pcy, __fmul_rn(0.5f, ph));
  bx1 = fminf(fmaxf(bx1, 0.f), 2559.f);
  by1 = fminf(fmaxf(by1, 0.f), 1535.f);
  bx2 = fminf(fmaxf(bx2, 0.f), 2559.f);
  by2 = fminf(fmaxf(by2, 0.f), 1535.f);
  const float bw = __fadd_rn(__fsub_rn(bx2, bx1), 1.f);
  const float bh = __fadd_rn(__fsub_rn(by2, by1), 1.f);
  float sc = s[g];
  if (!(bw >= 16.f && bh >= 16.f)) sc = -1e30f;

  float4 bo;
  bo.x = bx1; bo.y = by1; bo.z = bx2; bo.w = by2;
  *(float4*)&boxes[(size_t)g * 4] = bo;

  u32 sb = __float_as_uint(sc);
  u32 ou = (sb & 0x80000000u) ? ~sb : (sb | 0x80000000u);
  keys[g] = ((u64)ou << 32) | (u32)(~(u32)i);
}

// ---- fused select (exact rank-2000 threshold, 6-pass radix) + compact, per batch ----
__global__ __launch_bounds__(1024) void selcomp_k(const u64* __restrict__ keys,
                                                  u64* __restrict__ sel) {
  __shared__ u32 h[2048];
  __shared__ int s_bin;
  __shared__ u32 s_above;
  __shared__ int sc;
  const int b = blockIdx.x;
  const int tid = threadIdx.x;
  const u64* kb = keys + (size_t)b * 34560;
  u64 prefix = 0, pmask = 0;
  int rank = 2000;

#pragma unroll 1
  for (int pass = 0; pass < 6; ++pass) {
    int shift = 53 - 11 * pass;
    if (shift < 0) shift = 0;
    h[tid] = 0; h[tid + 1024] = 0;
    __syncthreads();
    for (int i = tid; i < 34560; i += 1024) {
      u64 k = kb[i];
      if ((k & pmask) == prefix)
        atomicAdd(&h[(u32)((k >> shift) & 2047ull)], 1u);
    }
    __syncthreads();
    // suffix sum: h[i] = count with bin >= i
    for (int off = 1; off < 2048; off <<= 1) {
      u32 t0, t1;
      { int i = tid;        t0 = h[i] + ((i + off < 2048) ? h[i + off] : 0u); }
      { int i = tid + 1024; t1 = h[i] + ((i + off < 2048) ? h[i + off] : 0u); }
      __syncthreads();
      h[tid] = t0; h[tid + 1024] = t1;
      __syncthreads();
    }
#pragma unroll
    for (int q = 0; q < 2; ++q) {
      int i = tid + 1024 * q;
      u32 Si = h[i];
      u32 Sn = (i < 2047) ? h[i + 1] : 0u;
      if ((int)Si >= rank && (int)Sn < rank) { s_bin = i; s_above = Sn; }
    }
    __syncthreads();
    rank -= (int)s_above;
    prefix |= ((u64)(u32)s_bin) << shift;
    pmask |= (2047ull << shift);
    __syncthreads();
  }
  // compact: keys >= prefix (exactly 2000, unordered)
  if (tid == 0) sc = 0;
  __syncthreads();
  for (int i = tid; i < 34560; i += 1024) {
    u64 k = kb[i];
    if (k >= prefix) {
      int p = atomicAdd(&sc, 1);
      sel[(size_t)b * 2048 + p] = k;
    }
  }
}

// ---------------- fused sort(2048) + greedy NMS per batch ----------------
__global__ __launch_bounds__(1024) void nms2_k(const u64* __restrict__ sel,
                                               const float* __restrict__ boxes,
                                               float* __restrict__ out) {
  __shared__ u64 K[2048];
  __shared__ float bx1[2000], by1[2000], bx2[2000], by2[2000], ar[2000];
  __shared__ unsigned char val[2000];
  __shared__ int s_pick, s_cur, s_cnt;
  const int b = blockIdx.x;
  const int tid = threadIdx.x;

  for (int i = tid; i < 2048; i += 1024)
    K[i] = (i < 2000) ? sel[(size_t)b * 2048 + i] : 0ull;
  __syncthreads();
  // bitonic sort descending
  for (int k2 = 2; k2 <= 2048; k2 <<= 1) {
    for (int j = k2 >> 1; j > 0; j >>= 1) {
      for (int i = tid; i < 2048; i += 1024) {
        int l = i ^ j;
        if (l > i) {
          u64 a = K[i], c = K[l];
          bool up = ((i & k2) == 0);
          if (up ? (a < c) : (a > c)) { K[i] = c; K[l] = a; }
        }
      }
      __syncthreads();
    }
  }
  // extract boxes/validity in score order
  for (int i = tid; i < 2000; i += 1024) {
    u64 key = K[i];
    u32 ou = (u32)(key >> 32);
    int idx = (int)(~(u32)key);
    u32 sb = (ou & 0x80000000u) ? (ou & 0x7FFFFFFFu) : ~ou;
    float sc = __uint_as_float(sb);
    const float4 bo = *(const float4*)&boxes[((size_t)b * 34560 + idx) * 4];
    bx1[i] = bo.x; by1[i] = bo.y; bx2[i] = bo.z; by2[i] = bo.w;
    ar[i] = __fmul_rn(__fadd_rn(__fsub_rn(bo.z, bo.x), 1.f),
                      __fadd_rn(__fsub_rn(bo.w, bo.y), 1.f));
    val[i] = (sc > -5e29f) ? 1 : 0;
  }
  if (tid == 0) { s_cur = 0; s_cnt = 0; }
  __syncthreads();

  for (int t = 0; t < 300; ++t) {
    if (tid == 0) {
      int c = s_cur;
      while (c < 2000 && !val[c]) ++c;
      if (c < 2000) { s_pick = c; s_cur = c + 1; s_cnt = t + 1; }
      else s_pick = -1;
    }
    __syncthreads();
    const int p = s_pick;
    if (p < 0) break;
    const float px1 = bx1[p], py1 = by1[p], px2 = bx2[p], py2 = by2[p], pa = ar[p];
    if (tid == 0) {
      float* row = out + ((size_t)b * 300 + t) * 5;
      row[0] = (float)b; row[1] = px1; row[2] = py1; row[3] = px2; row[4] = py2;
    }
    for (int jj = p + 1 + tid; jj < 2000; jj += 1024) {
      if (val[jj]) {
        float iw = __fadd_rn(__fsub_rn(fminf(px2, bx2[jj]), fmaxf(px1, bx1[jj])), 1.f);
        iw = fmaxf(0.f, iw);
        float ih = __fadd_rn(__fsub_rn(fminf(py2, by2[jj]), fmaxf(py1, by1[jj])), 1.f);
        ih = fmaxf(0.f, ih);
        float inter = __fmul_rn(iw, ih);
        float denom = __fsub_rn(__fadd_rn(pa, ar[jj]), inter);
        float iou = __fdiv_rn(inter, denom);
        if (iou > 0.7f) val[jj] = 0;
      }
    }
    __syncthreads();
  }

  __syncthreads();
  const int cnt = s_cnt;
  for (int t = cnt + tid; t < 300; t += 1024) {
    float* row = out + ((size_t)b * 300 + t) * 5;
    row[0] = (float)b; row[1] = 0.f; row[2] = 0.f; row[3] = 0.f; row[4] = 0.f;
  }
  if (tid == 0) out[6000 + b] = (float)cnt;
}

// ---------------- launcher ----------------
extern "C" void kernel_launch(void* const* d_in, const int* in_sizes, int n_in,
                              void* d_out, int out_size, void* d_ws, size_t ws_size,
                              hipStream_t stream) {
  const float* x  = (const float*)d_in[0];
  const float* w1 = (const float*)d_in[1];
  const float* b1 = (const float*)d_in[2];
  const float* wb = (const float*)d_in[3];
  const float* bb = (const float*)d_in[4];
  const float* wc = (const float*)d_in[5];
  const float* bc = (const float*)d_in[6];
  float* out = (float*)d_out;
  char* ws = (char*)d_ws;

  float* feat   = (float*)(ws + 0);           // 31,457,280 B
  float* wt2    = (float*)(ws + 31457280);    //  9,437,184 B
  float* deltas = (float*)(ws + 40894464);    //  2,211,840 B
  float* s      = (float*)(ws + 43106304);    //    552,960 B
  float* boxes  = (float*)(ws + 43659264);    //  2,211,840 B
  u64*   keys   = (u64*)  (ws + 45871104);    //  1,105,920 B
  u64*   sel    = (u64*)  (ws + 46977088);    //     65,536 B

  hipLaunchKernelGGL(transpose_k, dim3(9216), dim3(256), 0, stream, w1, wt2);
  hipLaunchKernelGGL(conv1_k, dim3(16, 12, 4), dim3(256), 0, stream, x, wt2, b1, feat);
  hipLaunchKernelGGL(heads_k, dim3(312), dim3(256), 0, stream, feat, wb, bb, wc, bc, deltas, s);
  hipLaunchKernelGGL(decode_k, dim3(540), dim3(256), 0, stream, deltas, s, boxes, keys);
  hipLaunchKernelGGL(selcomp_k, dim3(4), dim3(1024), 0, stream, keys, sel);
  hipLaunchKernelGGL(nms2_k, dim3(4), dim3(1024), 0, stream, sel, boxes, out);
}

// Round 8
// 1598.856 us; speedup vs baseline: 1.8952x; 1.1157x over previous
//
#include <hip/hip_runtime.h>
#include <stdint.h>

typedef unsigned long long u64;
typedef unsigned int u32;

// anchor (w,h) per a = ratio_idx*3 + scale_idx ; ratios (.5,1,2), scales (8,16,32)
__constant__ float c_aw[9] = {184.f,368.f,736.f,128.f,256.f,512.f, 88.f,176.f,352.f};
__constant__ float c_ah[9] = { 96.f,192.f,384.f,128.f,256.f,512.f,176.f,352.f,704.f};

// -------- w1 reorder: w1[co][ci*9+k] -> wt2[g][ci][k][m], co = g*8+m ----------
__global__ __launch_bounds__(256) void transpose_k(const float* __restrict__ w1,
                                                   float* __restrict__ wt2) {
  int e = blockIdx.x * 256 + threadIdx.x;   // < 2359296 exactly
  int m = e & 7;
  int t = e >> 3;
  int k = t % 9;
  int r = t / 9;          // g*512 + ci
  int ci = r & 511;
  int g = r >> 9;
  wt2[e] = w1[(size_t)(g * 8 + m) * 4608 + ci * 9 + k];
}

// ---------------- conv1: x(4,512,96,160) * w s2 p1 -> feat(4,512,48,80)
// block tile: 32co x 4oh x 80ow, 4 waves, wave = one co-group of 8.
// c0-level software pipeline: next chunk's x held in 48 regs during compute,
// ds_write after the compute barrier -> HBM latency hidden under VALU.
// accumulation order (c0 by 8, ci, kh, kw) bitwise matches all passing rounds.
__global__ __launch_bounds__(256, 3) void conv1_k(const float* __restrict__ x,
                                                  const float* __restrict__ wt2,
                                                  const float* __restrict__ b1,
                                                  float* __restrict__ feat) {
  __shared__ float xs[8 * 9 * 164];   // [ci][ih(9)][iw(161) pad 164] = 47232 B
  const int tid = threadIdx.x;
  const int lane = tid & 63;
  const int wv = __builtin_amdgcn_readfirstlane(tid >> 6);   // wave id 0..3
  const int owg = lane & 15;          // 16 groups of 5 ow
  const int ohl = lane >> 4;          // 0..3
  const int n = blockIdx.z;
  const int gg = blockIdx.x * 4 + wv; // global co-group, co = gg*8+m
  const int oh0 = blockIdx.y * 4;
  const int ih_base = 2 * oh0 - 1;

  // ---- c0-invariant staging descriptors (6 strided passes over 1449 elems) ----
  int soff[6], loff[6];
  float okf[6];
  bool act[6];
#pragma unroll
  for (int it = 0; it < 6; ++it) {
    int e2 = tid + 256 * it;
    act[it] = (e2 < 1449);
    int e = act[it] ? e2 : 0;
    int ih = e / 161;
    int c = e - ih * 161;
    int gih = ih_base + ih;
    int giw = c - 1;
    bool ok = act[it] && ((unsigned)gih < 96u) && ((unsigned)giw < 160u);
    int cg = min(max(gih, 0), 95);
    int cw = min(max(giw, 0), 159);
    soff[it] = cg * 160 + cw;           // clamped, always-valid global offset
    loff[it] = ih * 164 + c;
    okf[it] = ok ? 1.f : 0.f;
  }

  float acc[8][5];
#pragma unroll
  for (int m = 0; m < 8; ++m)
#pragma unroll
    for (int j = 0; j < 5; ++j) acc[m][j] = 0.f;

  const float* xb = x + (size_t)n * 512 * 96 * 160;
  const float* wgb = wt2 + (size_t)gg * 512 * 72;   // [ci][k(9)][m(8)]

  // prologue: load chunk c0=0 into regs
  float r[6][8];
#pragma unroll
  for (int it = 0; it < 6; ++it)
#pragma unroll
    for (int ci = 0; ci < 8; ++ci)
      r[it][ci] = xb[(size_t)ci * 15360 + soff[it]];

  for (int c0 = 0; c0 < 512; c0 += 8) {
    __syncthreads();   // previous compute finished; xs free for overwrite
#pragma unroll
    for (int it = 0; it < 6; ++it) {
      if (act[it]) {
        const float m_ = okf[it];
#pragma unroll
        for (int ci = 0; ci < 8; ++ci)
          xs[loff[it] + ci * 1476] = m_ * r[it][ci];   // 1476 = 9*164
      }
    }
    __syncthreads();
    // issue prefetch for c0+8 (fly during compute below)
    if (c0 + 8 < 512) {
      const float* xn = xb + (size_t)(c0 + 8) * 15360;
#pragma unroll
      for (int it = 0; it < 6; ++it)
#pragma unroll
        for (int ci = 0; ci < 8; ++ci)
          r[it][ci] = xn[(size_t)ci * 15360 + soff[it]];
    }

    for (int ci = 0; ci < 8; ++ci) {
      const float* wp = wgb + (size_t)(c0 + ci) * 72;   // wave-uniform
      const float* xrow = &xs[(ci * 9 + 2 * ohl) * 164 + owg * 10];
#pragma unroll
      for (int kh = 0; kh < 3; ++kh) {
        float xv[12];
        const float* xr = xrow + kh * 164;
#pragma unroll
        for (int t2 = 0; t2 < 6; ++t2) {          // 8B-aligned b64 LDS reads
          float2 t = *(const float2*)(xr + 2 * t2);
          xv[2 * t2] = t.x; xv[2 * t2 + 1] = t.y;
        }
#pragma unroll
        for (int kw = 0; kw < 3; ++kw) {
          const float* wk = wp + (kh * 3 + kw) * 8;
#pragma unroll
          for (int j = 0; j < 5; ++j) {
            const float xj = xv[kw + 2 * j];
            acc[0][j] += wk[0] * xj; acc[1][j] += wk[1] * xj;
            acc[2][j] += wk[2] * xj; acc[3][j] += wk[3] * xj;
            acc[4][j] += wk[4] * xj; acc[5][j] += wk[5] * xj;
            acc[6][j] += wk[6] * xj; acc[7][j] += wk[7] * xj;
          }
        }
      }
    }
  }
  // epilogue
  const int oh = oh0 + ohl;
  const int owb = owg * 5;
#pragma unroll
  for (int m = 0; m < 8; ++m) {
    const int co = gg * 8 + m;
    const float bv = b1[co];
    float* op = &feat[(((size_t)n * 512 + co) * 48 + oh) * 80 + owb];
#pragma unroll
    for (int j = 0; j < 5; ++j) op[j] = acc[m][j] + bv;
  }
}

// ---------------- fused heads: blocks [0,120) = conv2 (1x1 bbox), [120,312) = conv3 (3x3 cls)
__global__ __launch_bounds__(256) void heads_k(const float* __restrict__ feat,
                                               const float* __restrict__ wb,
                                               const float* __restrict__ bb,
                                               const float* __restrict__ wcg,
                                               const float* __restrict__ bc,
                                               float* __restrict__ deltas,
                                               float* __restrict__ s) {
  __shared__ float smem[5328];
  const int tid = threadIdx.x;

  if (blockIdx.x < 120) {
    // ---- conv2: 1x1, feat -> deltas[b][pos][36] ----
    float* fs  = smem;          // 16*128
    float* wsb = smem + 2048;   // 16*36
    const int blk = blockIdx.x;
    const int b = blk / 30;
    const int pos0 = (blk % 30) * 128;
    const int pl = tid >> 1, cg = tid & 1;
    const int cbase = cg * 18;
    float acc[18];
#pragma unroll
    for (int j = 0; j < 18; ++j) acc[j] = 0.f;
    const float* fb = feat + (size_t)b * 512 * 3840;

    for (int c0 = 0; c0 < 512; c0 += 16) {
      for (int e = tid; e < 16 * 128; e += 256)
        fs[e] = fb[(size_t)(c0 + (e >> 7)) * 3840 + pos0 + (e & 127)];
      for (int e = tid; e < 16 * 36; e += 256) {
        int ci = e / 36, c = e - ci * 36;
        wsb[e] = wb[(size_t)c * 512 + c0 + ci];
      }
      __syncthreads();
      for (int ci = 0; ci < 16; ++ci) {
        float xv = fs[ci * 128 + pl];
#pragma unroll
        for (int j = 0; j < 18; ++j) acc[j] += xv * wsb[ci * 36 + cbase + j];
      }
      __syncthreads();
    }
    size_t o = ((size_t)b * 3840 + pos0 + pl) * 36 + cbase;
#pragma unroll
    for (int j = 0; j < 18; ++j) deltas[o + j] = acc[j] + bb[cbase + j];
  } else {
    // ---- conv3: 3x3 p1, cls channels 9..17 -> s[b][pos*9+a] ----
    float (*fs)[3][84] = (float(*)[3][84])smem;           // 16*3*84 = 4032
    float (*wc)[9][9]  = (float(*)[9][9])(smem + 4032);   // 16*81 = 1296
    const int bid2 = blockIdx.x - 120;
    const int oh = bid2 % 48;
    const int b = bid2 / 48;
    const int pos = tid % 80;
    const int cg = tid / 80;          // 0..3 (cg==3 idle for compute)
    float acc[3] = {0.f, 0.f, 0.f};
    const float* fb = feat + (size_t)b * 512 * 3840;

    for (int c0 = 0; c0 < 512; c0 += 16) {
      for (int e = tid; e < 16 * 246; e += 256) {
        int ci = e / 246;
        int r = e - ci * 246;
        int ihl = r / 82;
        int iw = r - ihl * 82 - 1;
        int gih = oh - 1 + ihl;
        float v = 0.f;
        if ((unsigned)gih < 48u && (unsigned)iw < 80u)
          v = fb[(size_t)(c0 + ci) * 3840 + gih * 80 + iw];
        fs[ci][ihl][iw + 1] = v;
      }
      for (int e = tid; e < 16 * 81; e += 256) {
        int ci = e / 81;
        int r = e - ci * 81;
        int co = r / 9;
        int k = r - co * 9;
        wc[ci][co][k] = wcg[((size_t)(9 + co) * 512 + c0 + ci) * 9 + k];
      }
      __syncthreads();
      if (cg < 3) {
        const int cb = cg * 3;
        for (int ci = 0; ci < 16; ++ci) {
#pragma unroll
          for (int kh = 0; kh < 3; ++kh) {
#pragma unroll
            for (int kw = 0; kw < 3; ++kw) {
              float xv = fs[ci][kh][pos + kw];
              acc[0] += xv * wc[ci][cb + 0][kh * 3 + kw];
              acc[1] += xv * wc[ci][cb + 1][kh * 3 + kw];
              acc[2] += xv * wc[ci][cb + 2][kh * 3 + kw];
            }
          }
        }
      }
      __syncthreads();
    }
    if (cg < 3) {
      const int cb = cg * 3;
      size_t o = (size_t)b * 34560 + ((size_t)oh * 80 + pos) * 9 + cb;
#pragma unroll
      for (int j = 0; j < 3; ++j) s[o + j] = acc[j] + bc[9 + cb + j];
    }
  }
}

// ---------------- decode: anchors + deltas -> boxes, filtered score keys ----------------
__global__ __launch_bounds__(256) void decode_k(const float* __restrict__ deltas,
                                                const float* __restrict__ s,
                                                float* __restrict__ boxes,
                                                u64* __restrict__ keys) {
  const int g = blockIdx.x * 256 + threadIdx.x;  // < 138240 exactly
  const int b = g / 34560;
  const int i = g - b * 34560;
  const int pos = i / 9;
  const int a = i - pos * 9;
  const int h = pos / 80;
  const int w = pos - h * 80;
  const float gx = (float)(w * 32);
  const float gy = (float)(h * 32);
  const float aw = c_aw[a], ah = c_ah[a];
  const float x1a = 7.5f - 0.5f * (aw - 1.f);   // exact
  const float y1a = 7.5f - 0.5f * (ah - 1.f);   // exact
  const float ws_ = aw, hs_ = ah;               // x2-x1+1 exact
  const float cx = (gx + x1a) + 0.5f * ws_;     // exact
  const float cy = (gy + y1a) + 0.5f * hs_;     // exact

  const float* dp = &deltas[((size_t)b * 3840 + pos) * 36 + a * 4];
  const float d0 = dp[0], d1 = dp[1], d2 = dp[2], d3 = dp[3];
  const float pcx = __fadd_rn(__fmul_rn(d0, ws_), cx);
  const float pcy = __fadd_rn(__fmul_rn(d1, hs_), cy);
  const float pw = __fmul_rn(expf(d2), ws_);
  const float ph = __fmul_rn(expf(d3), hs_);
  float bx1 = __fsub_rn(pcx, __fmul_rn(0.5f, pw));
  float by1 = __fsub_rn(pcy, __fmul_rn(0.5f, ph));
  float bx2 = __fadd_rn(pcx, __fmul_rn(0.5f, pw));
  float by2 = __fadd_rn(pcy, __fmul_rn(0.5f, ph));
  bx1 = fminf(fmaxf(bx1, 0.f), 2559.f);
  by1 = fminf(fmaxf(by1, 0.f), 1535.f);
  bx2 = fminf(fmaxf(bx2, 0.f), 2559.f);
  by2 = fminf(fmaxf(by2, 0.f), 1535.f);
  const float bw = __fadd_rn(__fsub_rn(bx2, bx1), 1.f);
  const float bh = __fadd_rn(__fsub_rn(by2, by1), 1.f);
  float sc = s[g];
  if (!(bw >= 16.f && bh >= 16.f)) sc = -1e30f;

  float4 bo;
  bo.x = bx1; bo.y = by1; bo.z = bx2; bo.w = by2;
  *(float4*)&boxes[(size_t)g * 4] = bo;

  u32 sb = __float_as_uint(sc);
  u32 ou = (sb & 0x80000000u) ? ~sb : (sb | 0x80000000u);
  keys[g] = ((u64)ou << 32) | (u32)(~(u32)i);
}

// ---- fused select (exact rank-2000 threshold, 6-pass radix) + compact, per batch ----
__global__ __launch_bounds__(1024) void selcomp_k(const u64* __restrict__ keys,
                                                  u64* __restrict__ sel) {
  __shared__ u32 h[2048];
  __shared__ int s_bin;
  __shared__ u32 s_above;
  __shared__ int sc;
  const int b = blockIdx.x;
  const int tid = threadIdx.x;
  const u64* kb = keys + (size_t)b * 34560;
  u64 prefix = 0, pmask = 0;
  int rank = 2000;

#pragma unroll 1
  for (int pass = 0; pass < 6; ++pass) {
    int shift = 53 - 11 * pass;
    if (shift < 0) shift = 0;
    h[tid] = 0; h[tid + 1024] = 0;
    __syncthreads();
    for (int i = tid; i < 34560; i += 1024) {
      u64 k = kb[i];
      if ((k & pmask) == prefix)
        atomicAdd(&h[(u32)((k >> shift) & 2047ull)], 1u);
    }
    __syncthreads();
    // suffix sum: h[i] = count with bin >= i
    for (int off = 1; off < 2048; off <<= 1) {
      u32 t0, t1;
      { int i = tid;        t0 = h[i] + ((i + off < 2048) ? h[i + off] : 0u); }
      { int i = tid + 1024; t1 = h[i] + ((i + off < 2048) ? h[i + off] : 0u); }
      __syncthreads();
      h[tid] = t0; h[tid + 1024] = t1;
      __syncthreads();
    }
#pragma unroll
    for (int q = 0; q < 2; ++q) {
      int i = tid + 1024 * q;
      u32 Si = h[i];
      u32 Sn = (i < 2047) ? h[i + 1] : 0u;
      if ((int)Si >= rank && (int)Sn < rank) { s_bin = i; s_above = Sn; }
    }
    __syncthreads();
    rank -= (int)s_above;
    prefix |= ((u64)(u32)s_bin) << shift;
    pmask |= (2047ull << shift);
    __syncthreads();
  }
  // compact: keys >= prefix (exactly 2000, unordered)
  if (tid == 0) sc = 0;
  __syncthreads();
  for (int i = tid; i < 34560; i += 1024) {
    u64 k = kb[i];
    if (k >= prefix) {
      int p = atomicAdd(&sc, 1);
      sel[(size_t)b * 2048 + p] = k;
    }
  }
}

// ---------------- fused sort(2048) + greedy NMS per batch ----------------
__global__ __launch_bounds__(1024) void nms2_k(const u64* __restrict__ sel,
                                               const float* __restrict__ boxes,
                                               float* __restrict__ out) {
  __shared__ u64 K[2048];
  __shared__ float bx1[2000], by1[2000], bx2[2000], by2[2000], ar[2000];
  __shared__ unsigned char val[2000];
  __shared__ int s_pick, s_cur, s_cnt;
  const int b = blockIdx.x;
  const int tid = threadIdx.x;

  for (int i = tid; i < 2048; i += 1024)
    K[i] = (i < 2000) ? sel[(size_t)b * 2048 + i] : 0ull;
  __syncthreads();
  // bitonic sort descending
  for (int k2 = 2; k2 <= 2048; k2 <<= 1) {
    for (int j = k2 >> 1; j > 0; j >>= 1) {
      for (int i = tid; i < 2048; i += 1024) {
        int l = i ^ j;
        if (l > i) {
          u64 a = K[i], c = K[l];
          bool up = ((i & k2) == 0);
          if (up ? (a < c) : (a > c)) { K[i] = c; K[l] = a; }
        }
      }
      __syncthreads();
    }
  }
  // extract boxes/validity in score order
  for (int i = tid; i < 2000; i += 1024) {
    u64 key = K[i];
    u32 ou = (u32)(key >> 32);
    int idx = (int)(~(u32)key);
    u32 sb = (ou & 0x80000000u) ? (ou & 0x7FFFFFFFu) : ~ou;
    float sc = __uint_as_float(sb);
    const float4 bo = *(const float4*)&boxes[((size_t)b * 34560 + idx) * 4];
    bx1[i] = bo.x; by1[i] = bo.y; bx2[i] = bo.z; by2[i] = bo.w;
    ar[i] = __fmul_rn(__fadd_rn(__fsub_rn(bo.z, bo.x), 1.f),
                      __fadd_rn(__fsub_rn(bo.w, bo.y), 1.f));
    val[i] = (sc > -5e29f) ? 1 : 0;
  }
  if (tid == 0) { s_cur = 0; s_cnt = 0; }
  __syncthreads();

  for (int t = 0; t < 300; ++t) {
    if (tid == 0) {
      int c = s_cur;
      while (c < 2000 && !val[c]) ++c;
      if (c < 2000) { s_pick = c; s_cur = c + 1; s_cnt = t + 1; }
      else s_pick = -1;
    }
    __syncthreads();
    const int p = s_pick;
    if (p < 0) break;
    const float px1 = bx1[p], py1 = by1[p], px2 = bx2[p], py2 = by2[p], pa = ar[p];
    if (tid == 0) {
      float* row = out + ((size_t)b * 300 + t) * 5;
      row[0] = (float)b; row[1] = px1; row[2] = py1; row[3] = px2; row[4] = py2;
    }
    for (int jj = p + 1 + tid; jj < 2000; jj += 1024) {
      if (val[jj]) {
        float iw = __fadd_rn(__fsub_rn(fminf(px2, bx2[jj]), fmaxf(px1, bx1[jj])), 1.f);
        iw = fmaxf(0.f, iw);
        float ih = __fadd_rn(__fsub_rn(fminf(py2, by2[jj]), fmaxf(py1, by1[jj])), 1.f);
        ih = fmaxf(0.f, ih);
        float inter = __fmul_rn(iw, ih);
        float denom = __fsub_rn(__fadd_rn(pa, ar[jj]), inter);
        float iou = __fdiv_rn(inter, denom);
        if (iou > 0.7f) val[jj] = 0;
      }
    }
    __syncthreads();
  }

  __syncthreads();
  const int cnt = s_cnt;
  for (int t = cnt + tid; t < 300; t += 1024) {
    float* row = out + ((size_t)b * 300 + t) * 5;
    row[0] = (float)b; row[1] = 0.f; row[2] = 0.f; row[3] = 0.f; row[4] = 0.f;
  }
  if (tid == 0) out[6000 + b] = (float)cnt;
}

// ---------------- launcher ----------------
extern "C" void kernel_launch(void* const* d_in, const int* in_sizes, int n_in,
                              void* d_out, int out_size, void* d_ws, size_t ws_size,
                              hipStream_t stream) {
  const float* x  = (const float*)d_in[0];
  const float* w1 = (const float*)d_in[1];
  const float* b1 = (const float*)d_in[2];
  const float* wb = (const float*)d_in[3];
  const float* bb = (const float*)d_in[4];
  const float* wc = (const float*)d_in[5];
  const float* bc = (const float*)d_in[6];
  float* out = (float*)d_out;
  char* ws = (char*)d_ws;

  float* feat   = (float*)(ws + 0);           // 31,457,280 B
  float* wt2    = (float*)(ws + 31457280);    //  9,437,184 B
  float* deltas = (float*)(ws + 40894464);    //  2,211,840 B
  float* s      = (float*)(ws + 43106304);    //    552,960 B
  float* boxes  = (float*)(ws + 43659264);    //  2,211,840 B
  u64*   keys   = (u64*)  (ws + 45871104);    //  1,105,920 B
  u64*   sel    = (u64*)  (ws + 46977088);    //     65,536 B

  hipLaunchKernelGGL(transpose_k, dim3(9216), dim3(256), 0, stream, w1, wt2);
  hipLaunchKernelGGL(conv1_k, dim3(16, 12, 4), dim3(256), 0, stream, x, wt2, b1, feat);
  hipLaunchKernelGGL(heads_k, dim3(312), dim3(256), 0, stream, feat, wb, bb, wc, bc, deltas, s);
  hipLaunchKernelGGL(decode_k, dim3(540), dim3(256), 0, stream, deltas, s, boxes, keys);
  hipLaunchKernelGGL(selcomp_k, dim3(4), dim3(1024), 0, stream, keys, sel);
  hipLaunchKernelGGL(nms2_k, dim3(4), dim3(1024), 0, stream, sel, boxes, out);
}